// Round 3
// baseline (3355.344 us; speedup 1.0000x reference)
//
#include <hip/hip_runtime.h>
#include <hip/hip_cooperative_groups.h>

namespace cg = cooperative_groups;

typedef unsigned short u16;
typedef unsigned int   u32;
typedef __attribute__((ext_vector_type(8))) short short8;
typedef __attribute__((ext_vector_type(4))) short short4v;
typedef __attribute__((ext_vector_type(4))) float f32x4;

// up to 4 fused 1024x1024 NT products (C=A@B^T, optional C^T) riding along a
// dispatch as blocks x>=SQF; also carries the Q-power base for EPI=7.
struct SqJobs {
  const u16* a[4];
  const u16* b[4];
  u16* c[4];
  u16* ct[4];
};

__device__ __forceinline__ float bf2f(u16 v) {
  u32 x = ((u32)v) << 16;
  return __builtin_bit_cast(float, x);
}
__device__ __forceinline__ u16 f2bf(float f) {
  u32 x = __builtin_bit_cast(u32, f);
  x += 0x7FFFu + ((x >> 16) & 1u);
  return (u16)(x >> 16);
}
// async global->LDS, 16B/lane; LDS dest = wave-uniform base + lane*16
__device__ __forceinline__ void gload_lds16(const u16* g, u16* l) {
  __builtin_amdgcn_global_load_lds(
      (const __attribute__((address_space(1))) u32*)g,
      (__attribute__((address_space(3))) u32*)l, 16, 0, 0);
}

// ---------------------------------------------------------------------------
// NT GEMM: C[m,n] = sum_k A[m,k]*B[n,k]; bf16 MFMA 16x16x32, fp32 accum.
// K-loop: double-buffered LDS: issue next-tile stage, compute current tile,
// single barrier per K-step. fp32 operands load early / ds_write late.
// ADT/BDT: 0 bf16 operand (async global_load_lds), 1 fp32 (reg-convert)
// AMAP: 1 = Bnd shift map (p=row%257; p<shoff -> zero row, else row-shoff)
// EPI : 0 none; 2 +addf[8*row+jp1,n] fp32 guarded; 3 = 2 + write v to
//       Yout[8*row+jp1,n]; 4 +addf[row,n] fp32;
//       5 U-epilogue: +bias[n]; rows t%2048==0 take v=addf[row,n] (x fp32)
//         and also store to Yout[(row>>11)*257*1024+n] (Bnd0 p=0); rows
//         t%8==1 seed aux16[(row>>3),n] (Z0, bf16); fp32 C out
//       6 HS-final: +addf[row,n]; fp32 C out; rows p=row%257<256 also write
//         bf16 v to aux16[((row/257)*256+p),n]; 1<=p<256 also write v to
//         Yout[(b*2048+8p),n]
//       7 correction: j = blockIdx.z+1; B = (j==1 ? Bv : jb.a[0]+(j-2)*1M)
//         (= Q^j); v += addf[8*row+j,n]; write ONLY Yout[8*row+j,n]; no C.
// OMAP: 1 = out row (row>>8)*257 + (row&255) + 1 (Bnd layout)
// COUT: 0 bf16 out, 1 fp32 out.  TRW: 1 = also write bf16 C^T to aux16.
// SQF : >0 = blocks with blockIdx.x>=SQF run ride-along product
//       pi=(bx-SQF)>>4 from jb (16 x-tiles each, grid.y=16 covers n).
// LDS K-chunk swizzle: slot (r,c) holds global chunk c^(r&3); frag read uses
// column q^(lm&3) -> 16-lane quarters spread across all 32 banks.
// ---------------------------------------------------------------------------
template <int BM, int BN, int ADT, int BDT, int EPI, int AMAP, int OMAP,
          int COUT, int TRW, int SQF>
__global__ __launch_bounds__(256) void gemm_nt(
    const void* __restrict__ Av, int lda, const void* __restrict__ Bv, int ldb,
    void* __restrict__ Cv, int ldc, int Mrows, int K,
    const float* __restrict__ zrowF, const u16* __restrict__ zrowB,
    const float* __restrict__ bias, const float* __restrict__ addf,
    float* __restrict__ Yout, u16* __restrict__ aux16, int jp1, int shoff,
    SqJobs jb) {
  constexpr int WM = BM / 2, WN = BN / 2;
  constexpr int MT = WM / 16, NTT = WN / 16;
  constexpr int AIn = ADT ? BM * 8 : BM * 4;  // 16B issues for A tile
  constexpr int BIn = BDT ? BN * 8 : BN * 4;
  static_assert(AIn >= 256 && BIn >= 256, "tile too small for 256 threads");
  constexpr int AI = AIn / 256, BI = BIn / 256;
  constexpr int LA = BM * 32, LB = BN * 32;  // u16 elems per buffer
  __shared__ u16 lA[2 * LA];
  __shared__ u16 lB[2 * LB];
  const int tid = threadIdx.x;
  const int lane = tid & 63, wid = tid >> 6;
  const int wm = wid & 1, wn = wid >> 1;
  const bool role = (SQF > 0) && ((int)blockIdx.x >= SQF);
  const int pi = role ? (((int)blockIdx.x - SQF) >> 4) : 0;
  const int bxe = role ? (((int)blockIdx.x - SQF) & 15) : (int)blockIdx.x;
  const int m0 = bxe * BM, n0 = blockIdx.y * BN;
  const int effM = role ? 1024 : Mrows;
  const int q = lane >> 4, lm = lane & 15;
  const int cq = (q ^ (lm & 3)) * 8;  // swizzled frag column (u16 units)

  // EPI=7: per-z B operand (Q^j). z=0 -> Bv (=Q); z>=1 -> jb.a[0]+(z-1)*1M.
  const u16* corrB = nullptr;
  if constexpr (EPI == 7)
    corrB = (blockIdx.z == 0)
                ? (const u16*)Bv
                : jb.a[0] + (long)((int)blockIdx.z - 1) * 1048576;

  f32x4 acc[MT][NTT];
#pragma unroll
  for (int mi = 0; mi < MT; ++mi)
#pragma unroll
    for (int ni = 0; ni < NTT; ++ni) acc[mi][ni] = (f32x4){0.f, 0.f, 0.f, 0.f};

  const u16* aB[AI];
  const float* aF[AI];
#pragma unroll
  for (int i = 0; i < AI; ++i) {
    int g = tid + i * 256;
    int r = ADT ? (g >> 3) : (g >> 2);
    int c = ADT ? (g & 7) : (g & 3);
    int row = m0 + r;
    bool valid = (row < effM);
    if (AMAP == 1 && !role) {
      int p = row % 257;
      if (p < shoff) valid = false;
      row -= shoff;
    }
    if constexpr (ADT == 1) {
      int cs = ((((c >> 1) ^ (r & 3)) << 1) | (c & 1)) * 4;
      aF[i] = (valid ? (const float*)Av + (long)row * lda : zrowF) + cs;
    } else {
      int cs = (c ^ (r & 3)) * 8;
      const u16* base;
      if (role)
        base = jb.a[pi] + (long)row * 1024;
      else
        base = valid ? (const u16*)Av + (long)row * lda : zrowB;
      aB[i] = base + cs;
    }
  }
  const u16* bB[BI];
  const float* bF[BI];
#pragma unroll
  for (int i = 0; i < BI; ++i) {
    int g = tid + i * 256;
    int r = BDT ? (g >> 3) : (g >> 2);
    int c = BDT ? (g & 7) : (g & 3);
    if constexpr (BDT == 1) {
      int cs = ((((c >> 1) ^ (r & 3)) << 1) | (c & 1)) * 4;
      bF[i] = (const float*)Bv + (long)(n0 + r) * ldb + cs;
    } else {
      int cs = (c ^ (r & 3)) * 8;
      const u16* base;
      if (role) {
        base = jb.b[pi] + (long)(n0 + r) * 1024;
      } else {
        if constexpr (EPI == 7)
          base = corrB + (long)(n0 + r) * ldb;
        else
          base = (const u16*)Bv + (long)(n0 + r) * ldb;
      }
      bB[i] = base + cs;
    }
  }

  // --- prologue: stage tile 0 into buffer 0
  if constexpr (ADT == 1) {
    f32x4 f0[AI];
#pragma unroll
    for (int i = 0; i < AI; ++i) f0[i] = *(const f32x4*)(aF[i]);
#pragma unroll
    for (int i = 0; i < AI; ++i) {
      short4v s = {(short)f2bf(f0[i][0]), (short)f2bf(f0[i][1]),
                   (short)f2bf(f0[i][2]), (short)f2bf(f0[i][3])};
      *(short4v*)&lA[(tid + i * 256) * 4] = s;
    }
  } else {
#pragma unroll
    for (int i = 0; i < AI; ++i) gload_lds16(aB[i], &lA[(tid + i * 256) * 8]);
  }
  if constexpr (BDT == 1) {
    f32x4 f0[BI];
#pragma unroll
    for (int i = 0; i < BI; ++i) f0[i] = *(const f32x4*)(bF[i]);
#pragma unroll
    for (int i = 0; i < BI; ++i) {
      short4v s = {(short)f2bf(f0[i][0]), (short)f2bf(f0[i][1]),
                   (short)f2bf(f0[i][2]), (short)f2bf(f0[i][3])};
      *(short4v*)&lB[(tid + i * 256) * 4] = s;
    }
  } else {
#pragma unroll
    for (int i = 0; i < BI; ++i) gload_lds16(bB[i], &lB[(tid + i * 256) * 8]);
  }
  __syncthreads();  // tile 0 staged (vmcnt+lgkm drained)

  int cur = 0;
  for (int k0 = 0; k0 < K; k0 += 32) {
    const int kn = k0 + 32;
    const bool more = kn < K;
    const int nxA = (cur ^ 1) * LA, nxB = (cur ^ 1) * LB;
    f32x4 fa[AI], fb[BI];
    // issue next-tile global loads (stage-early)
    if (more) {
      if constexpr (ADT == 1) {
#pragma unroll
        for (int i = 0; i < AI; ++i) fa[i] = *(const f32x4*)(aF[i] + kn);
      } else {
#pragma unroll
        for (int i = 0; i < AI; ++i)
          gload_lds16(aB[i] + kn, &lA[nxA + (tid + i * 256) * 8]);
      }
      if constexpr (BDT == 1) {
#pragma unroll
        for (int i = 0; i < BI; ++i) fb[i] = *(const f32x4*)(bF[i] + kn);
      } else {
#pragma unroll
        for (int i = 0; i < BI; ++i)
          gload_lds16(bB[i] + kn, &lB[nxB + (tid + i * 256) * 8]);
      }
    }
    // compute current tile (hides the in-flight loads)
    short8 af[MT], bf[NTT];
#pragma unroll
    for (int mi = 0; mi < MT; ++mi)
      af[mi] =
          *(const short8*)&lA[cur * LA + (wm * WM + mi * 16 + lm) * 32 + cq];
#pragma unroll
    for (int ni = 0; ni < NTT; ++ni)
      bf[ni] =
          *(const short8*)&lB[cur * LB + (wn * WN + ni * 16 + lm) * 32 + cq];
#pragma unroll
    for (int mi = 0; mi < MT; ++mi)
#pragma unroll
      for (int ni = 0; ni < NTT; ++ni)
        acc[mi][ni] = __builtin_amdgcn_mfma_f32_16x16x32_bf16(
            af[mi], bf[ni], acc[mi][ni], 0, 0, 0);
    // late convert+ds_write for fp32 operands (vmcnt-wait lands post-MFMA)
    if (more) {
      if constexpr (ADT == 1) {
#pragma unroll
        for (int i = 0; i < AI; ++i) {
          short4v s = {(short)f2bf(fa[i][0]), (short)f2bf(fa[i][1]),
                       (short)f2bf(fa[i][2]), (short)f2bf(fa[i][3])};
          *(short4v*)&lA[nxA + (tid + i * 256) * 4] = s;
        }
      }
      if constexpr (BDT == 1) {
#pragma unroll
        for (int i = 0; i < BI; ++i) {
          short4v s = {(short)f2bf(fb[i][0]), (short)f2bf(fb[i][1]),
                       (short)f2bf(fb[i][2]), (short)f2bf(fb[i][3])};
          *(short4v*)&lB[nxB + (tid + i * 256) * 4] = s;
        }
      }
    }
    __syncthreads();  // next tile ready; current buffer free for overwrite
    cur ^= 1;
  }

#pragma unroll
  for (int mi = 0; mi < MT; ++mi) {
    int rbase = m0 + wm * WM + mi * 16 + q * 4;
#pragma unroll
    for (int ni = 0; ni < NTT; ++ni) {
      int ocol = n0 + wn * WN + ni * 16 + lm;
#pragma unroll
      for (int r = 0; r < 4; ++r) {
        int orow = rbase + r;
        float v = acc[mi][ni][r];
        if (role) {
          if (orow < 1024) {
            u16 ov = f2bf(v);
            jb.c[pi][(long)orow * 1024 + ocol] = ov;
            if (jb.ct[pi]) jb.ct[pi][(long)ocol * 1024 + orow] = ov;
          }
          continue;
        }
        if (orow >= Mrows) continue;
        if constexpr (EPI == 7) {
          long urow = 8L * orow + ((int)blockIdx.z + 1);
          float vv = v + addf[urow * 1024 + ocol];
          Yout[urow * 1024 + ocol] = vv;
          continue;
        }
        if constexpr (EPI == 5) {
          v += bias[ocol];
          bool isT0 = (orow & 2047) == 0;
          if (isT0) v = addf[(long)orow * 1024 + ocol];  // y0 = x[:,0] exact
          ((float*)Cv)[(long)orow * ldc + ocol] = v;
          if (isT0) Yout[((long)(orow >> 11) * 257) * 1024 + ocol] = v;
          if ((orow & 7) == 1)
            aux16[((long)(orow >> 3)) * 1024 + ocol] = f2bf(v);
          continue;
        }
        if constexpr (EPI == 6) {
          v += addf[(long)orow * 1024 + ocol];
          ((float*)Cv)[(long)orow * ldc + ocol] = v;
          int b = orow / 257;
          int pp_ = orow - b * 257;
          if (pp_ < 256)
            aux16[((long)(b * 256 + pp_)) * 1024 + ocol] = f2bf(v);
          if (pp_ >= 1 && pp_ < 256)
            Yout[((long)b * 2048 + 8L * pp_) * 1024 + ocol] = v;
          continue;
        }
        long urow = 0;
        bool uok = true;
        if constexpr (EPI == 2 || EPI == 3) {
          urow = 8L * orow + jp1;
          uok = ((urow & 2047) != 0);  // t==0 (mod L) slot invalid
          if (uok) v += addf[urow * 1024 + ocol];
        }
        if constexpr (EPI == 4) v += addf[(long)orow * 1024 + ocol];
        long wrow = orow;
        if constexpr (OMAP == 1)
          wrow = (long)(orow >> 8) * 257 + (orow & 255) + 1;
        if constexpr (COUT == 1)
          ((float*)Cv)[wrow * (long)ldc + ocol] = v;
        else
          ((u16*)Cv)[wrow * (long)ldc + ocol] = f2bf(v);
        if constexpr (TRW == 1) aux16[(long)ocol * ldc + orow] = f2bf(v);
        if constexpr (EPI == 3) {
          if (uok) Yout[urow * 1024 + ocol] = v;
        }
      }
    }
  }
}

// ---------------------------------------------------------------------------
// Cooperative fused scan: phase1 (6 chunk steps + boundary-final) + phase2
// (5 Hillis-Steele rounds) in ONE kernel, grid.sync() between the 12 stages.
// 64x64 tiles, dbuf K-loop identical to gemm_nt's. Ride-along squarings keep
// their slots (tiles >= 512 in phase-1 stages). Phase 3 stays a separate
// trailing dispatch (nothing depends on it inside the kernel).
// ---------------------------------------------------------------------------
struct ScanArgs {
  const u16* Qb; const u16* QbT;
  u16* Z0; u16* Z1;
  float* Y;
  float* B0; float* B1;
  u16* PW;  // Q^2..Q^7 contiguous (1M u16 stride)
  u16* Tb2; u16* Tt2; u16* Tb3; u16* Tt3; u16* Tb4; u16* Tt4;
  u16* Tb5; u16* Tt5; u16* Tb6; u16* Tt6;
  u16* Tt0; u16* Tt1; u16* P3T;
  const float* zF;
};

__device__ __forceinline__ void tile_bf16(const u16* Ab, const u16* Bb,
                                          int m0, int n0, u16* lA, u16* lB,
                                          int tid, int wm, int wn, int lm,
                                          int cq, f32x4 (&acc)[2][2]) {
#pragma unroll
  for (int mi = 0; mi < 2; ++mi)
#pragma unroll
    for (int ni = 0; ni < 2; ++ni) acc[mi][ni] = (f32x4){0.f, 0.f, 0.f, 0.f};
  const int r = tid >> 2, c = tid & 3;
  const int cs = (c ^ (r & 3)) * 8;
  const u16* ap = Ab + (long)(m0 + r) * 1024 + cs;
  const u16* bp = Bb + (long)(n0 + r) * 1024 + cs;
  gload_lds16(ap, &lA[tid * 8]);
  gload_lds16(bp, &lB[tid * 8]);
  __syncthreads();
  int cur = 0;
  for (int k0 = 0; k0 < 1024; k0 += 32) {
    const int kn = k0 + 32;
    const bool more = kn < 1024;
    const int nx = (cur ^ 1) * 2048;
    if (more) {
      gload_lds16(ap + kn, &lA[nx + tid * 8]);
      gload_lds16(bp + kn, &lB[nx + tid * 8]);
    }
    const int cb = cur * 2048;
    short8 a0 = *(const short8*)&lA[cb + (wm * 32 + lm) * 32 + cq];
    short8 a1 = *(const short8*)&lA[cb + (wm * 32 + 16 + lm) * 32 + cq];
    short8 b0 = *(const short8*)&lB[cb + (wn * 32 + lm) * 32 + cq];
    short8 b1 = *(const short8*)&lB[cb + (wn * 32 + 16 + lm) * 32 + cq];
    acc[0][0] =
        __builtin_amdgcn_mfma_f32_16x16x32_bf16(a0, b0, acc[0][0], 0, 0, 0);
    acc[0][1] =
        __builtin_amdgcn_mfma_f32_16x16x32_bf16(a0, b1, acc[0][1], 0, 0, 0);
    acc[1][0] =
        __builtin_amdgcn_mfma_f32_16x16x32_bf16(a1, b0, acc[1][0], 0, 0, 0);
    acc[1][1] =
        __builtin_amdgcn_mfma_f32_16x16x32_bf16(a1, b1, acc[1][1], 0, 0, 0);
    __syncthreads();
    cur ^= 1;
  }
}

__device__ __forceinline__ void tile_f32a(const float* Af, const u16* Bb,
                                          int m0, int n0, int shoff,
                                          const float* zF, u16* lA, u16* lB,
                                          int tid, int wm, int wn, int lm,
                                          int cq, f32x4 (&acc)[2][2]) {
#pragma unroll
  for (int mi = 0; mi < 2; ++mi)
#pragma unroll
    for (int ni = 0; ni < 2; ++ni) acc[mi][ni] = (f32x4){0.f, 0.f, 0.f, 0.f};
  const float* ap0;
  const float* ap1;
  {
    const int r = tid >> 3, c = tid & 7;
    const int row = m0 + r;
    const bool valid = (row < 2056) && ((row % 257) >= shoff);
    const int cs = ((((c >> 1) ^ (r & 3)) << 1) | (c & 1)) * 4;
    ap0 = (valid ? Af + (long)(row - shoff) * 1024 : zF) + cs;
  }
  {
    const int g = tid + 256;
    const int r = g >> 3, c = g & 7;
    const int row = m0 + r;
    const bool valid = (row < 2056) && ((row % 257) >= shoff);
    const int cs = ((((c >> 1) ^ (r & 3)) << 1) | (c & 1)) * 4;
    ap1 = (valid ? Af + (long)(row - shoff) * 1024 : zF) + cs;
  }
  const int rb = tid >> 2, cb2 = tid & 3;
  const u16* bp = Bb + (long)(n0 + rb) * 1024 + (cb2 ^ (rb & 3)) * 8;
  {
    f32x4 f0 = *(const f32x4*)ap0;
    f32x4 f1 = *(const f32x4*)ap1;
    gload_lds16(bp, &lB[tid * 8]);
    short4v s0 = {(short)f2bf(f0[0]), (short)f2bf(f0[1]), (short)f2bf(f0[2]),
                  (short)f2bf(f0[3])};
    *(short4v*)&lA[tid * 4] = s0;
    short4v s1 = {(short)f2bf(f1[0]), (short)f2bf(f1[1]), (short)f2bf(f1[2]),
                  (short)f2bf(f1[3])};
    *(short4v*)&lA[(tid + 256) * 4] = s1;
  }
  __syncthreads();
  int cur = 0;
  for (int k0 = 0; k0 < 1024; k0 += 32) {
    const int kn = k0 + 32;
    const bool more = kn < 1024;
    const int nx = (cur ^ 1) * 2048;
    f32x4 f0, f1;
    if (more) {
      f0 = *(const f32x4*)(ap0 + kn);
      f1 = *(const f32x4*)(ap1 + kn);
      gload_lds16(bp + kn, &lB[nx + tid * 8]);
    }
    const int cb = cur * 2048;
    short8 a0 = *(const short8*)&lA[cb + (wm * 32 + lm) * 32 + cq];
    short8 a1 = *(const short8*)&lA[cb + (wm * 32 + 16 + lm) * 32 + cq];
    short8 b0 = *(const short8*)&lB[cb + (wn * 32 + lm) * 32 + cq];
    short8 b1 = *(const short8*)&lB[cb + (wn * 32 + 16 + lm) * 32 + cq];
    acc[0][0] =
        __builtin_amdgcn_mfma_f32_16x16x32_bf16(a0, b0, acc[0][0], 0, 0, 0);
    acc[0][1] =
        __builtin_amdgcn_mfma_f32_16x16x32_bf16(a0, b1, acc[0][1], 0, 0, 0);
    acc[1][0] =
        __builtin_amdgcn_mfma_f32_16x16x32_bf16(a1, b0, acc[1][0], 0, 0, 0);
    acc[1][1] =
        __builtin_amdgcn_mfma_f32_16x16x32_bf16(a1, b1, acc[1][1], 0, 0, 0);
    if (more) {
      short4v s0 = {(short)f2bf(f0[0]), (short)f2bf(f0[1]), (short)f2bf(f0[2]),
                    (short)f2bf(f0[3])};
      *(short4v*)&lA[nx + tid * 4] = s0;
      short4v s1 = {(short)f2bf(f1[0]), (short)f2bf(f1[1]), (short)f2bf(f1[2]),
                    (short)f2bf(f1[3])};
      *(short4v*)&lA[nx + (tid + 256) * 4] = s1;
    }
    __syncthreads();
    cur ^= 1;
  }
}

__global__ __launch_bounds__(256, 4) void scan_all(ScanArgs a) {
  const long M1 = 1048576;
  cg::grid_group grid = cg::this_grid();
  __shared__ u16 lA[4096];
  __shared__ u16 lB[4096];
  const int tid = threadIdx.x;
  const int lane = tid & 63, wid = tid >> 6;
  const int wm = wid & 1, wn = wid >> 1;
  const int q = lane >> 4, lm = lane & 15;
  const int cq = (q ^ (lm & 3)) * 8;
  const int G = (int)gridDim.x;

  for (int s = 0; s < 12; ++s) {
    // ---- uniform stage descriptors ----
    int nt = 0, jps = 0, shoff = 0;
    const u16* zin = nullptr;
    u16* zout = nullptr;
    const u16* ra0 = nullptr; const u16* rb0 = nullptr;
    u16* rc0 = nullptr; u16* rct0 = nullptr;
    const u16* ra1 = nullptr; const u16* rb1 = nullptr;
    u16* rc1 = nullptr; u16* rct1 = nullptr;
    const u16* ra2 = nullptr; const u16* rb2 = nullptr;
    u16* rc2 = nullptr;
    const u16* ra3 = nullptr; const u16* rb3 = nullptr;
    u16* rc3 = nullptr;
    const float* bc = nullptr;
    float* bn = nullptr;
    const u16* Bp2 = nullptr;
    if (s < 6) {
      const int j = s + 1;
      zin = (j & 1) ? a.Z0 : a.Z1;
      zout = (j & 1) ? a.Z1 : a.Z0;
      jps = j + 1;
      int nr;
      if (s == 0) {
        nr = 1; ra0 = a.Qb; rb0 = a.QbT; rc0 = a.PW; rct0 = a.Tt0;
      } else if (s == 1) {
        nr = 2;
        ra0 = a.PW; rb0 = a.Tt0; rc0 = a.PW + 2 * M1; rct0 = a.Tt1;
        ra1 = a.PW; rb1 = a.QbT; rc1 = a.PW + 1 * M1; rct1 = a.P3T;
      } else if (s == 2) {
        nr = 4;
        ra0 = a.PW + 2 * M1; rb0 = a.Tt1; rc0 = a.Tb2; rct0 = a.Tt2;
        ra1 = a.PW + 2 * M1; rb1 = a.QbT; rc1 = a.PW + 3 * M1; rct1 = nullptr;
        ra2 = a.PW + 2 * M1; rb2 = a.Tt0; rc2 = a.PW + 4 * M1;
        ra3 = a.PW + 2 * M1; rb3 = a.P3T; rc3 = a.PW + 5 * M1;
      } else if (s == 3) {
        nr = 1; ra0 = a.Tb2; rb0 = a.Tt2; rc0 = a.Tb3; rct0 = a.Tt3;
      } else if (s == 4) {
        nr = 1; ra0 = a.Tb3; rb0 = a.Tt3; rc0 = a.Tb4; rct0 = a.Tt4;
      } else {
        nr = 1; ra0 = a.Tb4; rb0 = a.Tt4; rc0 = a.Tb5; rct0 = a.Tt5;
      }
      nt = 512 + 256 * nr;
    } else if (s == 6) {
      zin = a.Z0;
      jps = 8;
      ra0 = a.Tb5; rb0 = a.Tt5; rc0 = a.Tb6; rct0 = a.Tt6;
      nt = 768;
    } else {
      const int s2 = s - 7;
      bc = (s2 & 1) ? a.B1 : a.B0;
      bn = (s2 & 1) ? a.B0 : a.B1;
      shoff = 1 << s2;
      Bp2 = (s2 == 0)   ? a.Tb2
            : (s2 == 1) ? a.Tb3
            : (s2 == 2) ? a.Tb4
            : (s2 == 3) ? a.Tb5
                        : a.Tb6;
      nt = 528;
    }

    for (int t = blockIdx.x; t < nt; t += G) {
      f32x4 acc[2][2];
      if (s <= 6) {
        if (t < 512) {  // scan tile
          const int m0 = (t >> 4) * 64, n0 = (t & 15) * 64;
          tile_bf16(zin, a.Qb, m0, n0, lA, lB, tid, wm, wn, lm, cq, acc);
#pragma unroll
          for (int mi = 0; mi < 2; ++mi) {
            const int rbase = m0 + wm * 32 + mi * 16 + q * 4;
#pragma unroll
            for (int ni = 0; ni < 2; ++ni) {
              const int ocol = n0 + wn * 32 + ni * 16 + lm;
#pragma unroll
              for (int r = 0; r < 4; ++r) {
                const int orow = rbase + r;
                float v = acc[mi][ni][r];
                const long urow = 8L * orow + jps;
                const bool uok = ((urow & 2047) != 0);
                if (uok) v += a.Y[urow * 1024 + ocol];
                if (s < 6) {
                  zout[(long)orow * 1024 + ocol] = f2bf(v);
                  if (uok) a.Y[urow * 1024 + ocol] = v;
                } else {
                  const long wrow = (long)(orow >> 8) * 257 + (orow & 255) + 1;
                  a.B0[wrow * 1024 + ocol] = v;
                }
              }
            }
          }
        } else {  // ride-along squaring tile
          const int tt = t - 512;
          const int pi = tt >> 8, tl = tt & 255;
          const int m0 = (tl >> 4) * 64, n0 = (tl & 15) * 64;
          const u16* pa = ra0; const u16* pb = rb0;
          u16* pc = rc0; u16* pct = rct0;
          if (pi == 1) { pa = ra1; pb = rb1; pc = rc1; pct = rct1; }
          else if (pi == 2) { pa = ra2; pb = rb2; pc = rc2; pct = nullptr; }
          else if (pi == 3) { pa = ra3; pb = rb3; pc = rc3; pct = nullptr; }
          tile_bf16(pa, pb, m0, n0, lA, lB, tid, wm, wn, lm, cq, acc);
#pragma unroll
          for (int mi = 0; mi < 2; ++mi) {
            const int rbase = m0 + wm * 32 + mi * 16 + q * 4;
#pragma unroll
            for (int ni = 0; ni < 2; ++ni) {
              const int ocol = n0 + wn * 32 + ni * 16 + lm;
#pragma unroll
              for (int r = 0; r < 4; ++r) {
                const int orow = rbase + r;
                const u16 ov = f2bf(acc[mi][ni][r]);
                pc[(long)orow * 1024 + ocol] = ov;
                if (pct) pct[(long)ocol * 1024 + orow] = ov;
              }
            }
          }
        }
      } else {  // phase 2 (fp32 A with Bnd shift map)
        const int m0 = (t >> 4) * 64, n0 = (t & 15) * 64;
        tile_f32a(bc, Bp2, m0, n0, shoff, a.zF, lA, lB, tid, wm, wn, lm, cq,
                  acc);
#pragma unroll
        for (int mi = 0; mi < 2; ++mi) {
          const int rbase = m0 + wm * 32 + mi * 16 + q * 4;
#pragma unroll
          for (int ni = 0; ni < 2; ++ni) {
            const int ocol = n0 + wn * 32 + ni * 16 + lm;
#pragma unroll
            for (int r = 0; r < 4; ++r) {
              const int orow = rbase + r;
              if (orow >= 2056) continue;
              const float v = acc[mi][ni][r] + bc[(long)orow * 1024 + ocol];
              bn[(long)orow * 1024 + ocol] = v;
              if (s == 11) {
                const int b = orow / 257;
                const int pp = orow - b * 257;
                if (pp < 256)
                  a.Z0[((long)(b * 256 + pp)) * 1024 + ocol] = f2bf(v);
                if (pp >= 1 && pp < 256)
                  a.Y[((long)b * 2048 + 8L * pp) * 1024 + ocol] = v;
              }
            }
          }
        }
      }
    }
    __threadfence();
    grid.sync();
  }
}

// ---------------------------------------------------------------------------
// helpers
// ---------------------------------------------------------------------------
__global__ void zero_misc(float* zF, u16* zB) {
  for (int i = threadIdx.x; i < 2048; i += 256) {
    zF[i] = 0.f;
    zB[i] = 0;
  }
}
__global__ void xconv(const float* __restrict__ x, u16* __restrict__ xb) {
  long i = (long)blockIdx.x * 256 + threadIdx.x;  // 4 elems/thread
  f32x4 v = ((const f32x4*)x)[i];
  short4v s = {(short)f2bf(v[0]), (short)f2bf(v[1]), (short)f2bf(v[2]),
               (short)f2bf(v[3])};
  ((short4v*)xb)[i] = s;
}
// WxT[d,k] = rc_w[k,d]; WyT[d,k] = rc_w[k,1024+d] + rc_w[k,2048+d]
__global__ void prep_wt(const float* __restrict__ rc_w, u16* __restrict__ WxT,
                        u16* __restrict__ WyT) {
  __shared__ u16 tx[64][65];
  __shared__ u16 ty[64][65];
  int kb = blockIdx.x * 64, db = blockIdx.y * 64;
  for (int i = threadIdx.x; i < 64 * 64; i += 256) {
    int r = i >> 6, c = i & 63;
    long base = (long)(kb + r) * 3072 + db + c;
    tx[r][c] = f2bf(rc_w[base]);
    ty[r][c] = f2bf(rc_w[base + 1024] + rc_w[base + 2048]);
  }
  __syncthreads();
  for (int i = threadIdx.x; i < 64 * 64; i += 256) {
    int r = i >> 6, c = i & 63;
    WxT[(long)(db + r) * 1024 + kb + c] = tx[c][r];
    WyT[(long)(db + r) * 1024 + kb + c] = ty[c][r];
  }
}
__global__ void matvec_c(const u16* __restrict__ M_,
                         const float* __restrict__ rb,
                         float* __restrict__ cvec) {
  int row = blockIdx.x;
  int lane = threadIdx.x;
  float s = 0.f;
  for (int k = lane; k < 1024; k += 64)
    s += bf2f(M_[(long)row * 1024 + k]) * rb[k];
  for (int o = 32; o > 0; o >>= 1) s += __shfl_down(s, o, 64);
  if (lane == 0) cvec[row] = s;
}

// ---------------------------------------------------------------------------
extern "C" void kernel_launch(void* const* d_in, const int* in_sizes, int n_in,
                              void* d_out, int out_size, void* d_ws,
                              size_t ws_size, hipStream_t stream) {
  const float* x = (const float*)d_in[0];
  const float* A_w = (const float*)d_in[1];
  const float* C_w = (const float*)d_in[2];
  const float* rc_w = (const float*)d_in[3];
  const float* rc_b = (const float*)d_in[4];
  float* Y = (float*)d_out;  // fp32 U, then final y (same-element RMW)

  char* ws = (char*)d_ws;
  const long MB = 1 << 20;
  u16* Z0 = (u16*)(ws);                 // 4 MB
  u16* Z1 = (u16*)(ws + 4 * MB);        // 4 MB
  float* Bnd0 = (float*)(ws + 8 * MB);  // 2056*1024*4 (reserve 8.5 MB)
  float* Bnd1 = (float*)(ws + 8 * MB + 8912896);
  char* p = ws + 25 * MB;
  u16* Mbuf = (u16*)p;                       // 2 MB
  u16* WxT = (u16*)(p + 2 * MB);             // 2 MB
  u16* WyT = (u16*)(p + 4 * MB);             // 2 MB
  u16* Pbuf = (u16*)(p + 6 * MB);            // 2 MB
  u16* Qbuf = (u16*)(p + 8 * MB);            // 2 MB
  u16* QbufT = (u16*)(p + 10 * MB);          // 2 MB
  float* cvec = (float*)(p + 12 * MB);       // 4 KB
  float* zF = (float*)(p + 12 * MB + 4096);  // 8 KB zeros
  u16* zB = (u16*)(p + 12 * MB + 12288);     // 4 KB zeros
  u16* xbf = (u16*)(p + 12 * MB + 16384);    // 32 MB: x-bf16, then powers
  const size_t need_fast = (size_t)(25 * MB + 12 * MB + 16384) + 33554432;
  const bool fast = ws_size >= need_fast;

  SqJobs J0{};
  dim3 blk(256);
  zero_misc<<<dim3(1), blk, 0, stream>>>(zF, zB);
  if (fast) xconv<<<dim3(16384), blk, 0, stream>>>(x, xbf);
  prep_wt<<<dim3(16, 16), blk, 0, stream>>>(rc_w, WxT, WyT);

  // M = C_w @ A_w (A symmetric -> NT), both fp32
  gemm_nt<64, 64, 1, 1, 0, 0, 0, 0, 0, 0><<<dim3(16, 16), blk, 0, stream>>>(
      C_w, 1024, A_w, 1024, Mbuf, 1024, 1024, 1024, zF, zB, nullptr, nullptr,
      nullptr, nullptr, 0, 0, J0);
  // Q = M @ Wy (emits Q^T too); P = M @ Wx rides along (blocks x>=16)
  SqJobs sjPQ{};
  sjPQ.a[0] = Mbuf;
  sjPQ.b[0] = WxT;
  sjPQ.c[0] = Pbuf;
  gemm_nt<64, 64, 0, 0, 0, 0, 0, 0, 1, 16><<<dim3(32, 16), blk, 0, stream>>>(
      Mbuf, 1024, WyT, 1024, Qbuf, 1024, 1024, 1024, zF, zB, nullptr, nullptr,
      nullptr, QbufT, 0, 0, sjPQ);
  matvec_c<<<dim3(1024), dim3(64), 0, stream>>>(Mbuf, rc_b, cvec);

  // U[t,:] = x[t,:]@P^T + c -> d_out fp32 (EPI5 also: y0/Bnd0-p0 from x,
  // Z0 seed rows t%8==1)
  if (fast)
    gemm_nt<128, 128, 0, 0, 5, 0, 0, 1, 0, 0>
        <<<dim3(128, 8), blk, 0, stream>>>(xbf, 1024, Pbuf, 1024, Y, 1024,
                                           16384, 1024, zF, zB, cvec, x, Bnd0,
                                           Z0, 0, 0, J0);
  else
    gemm_nt<128, 128, 1, 0, 5, 0, 0, 1, 0, 0>
        <<<dim3(128, 8), blk, 0, stream>>>(x, 1024, Pbuf, 1024, Y, 1024, 16384,
                                           1024, zF, zB, cvec, x, Bnd0, Z0, 0,
                                           0, J0);

  if (fast) {
    const long M1 = 1048576;  // one 1024x1024 bf16 matrix, in u16 elements
    u16* PW = xbf;            // slot j-2 = Q^j, j=2..7
    u16* Tb2 = xbf + 6 * M1;
    u16* Tt2 = xbf + 7 * M1;
    u16* Tb3 = xbf + 8 * M1;
    u16* Tt3 = xbf + 9 * M1;
    u16* Tb4 = xbf + 10 * M1;
    u16* Tt4 = xbf + 11 * M1;
    u16* Tb5 = xbf + 12 * M1;
    u16* Tt5 = xbf + 13 * M1;
    u16* Tb6 = xbf + 14 * M1;
    u16* Tt6 = xbf + 15 * M1;
    u16* Tt0 = Mbuf;
    u16* Tt1 = WxT;
    u16* Pw3T = WyT;

    // ---- cooperative fused scan (phase1 + phase2), 12 stages ----
    ScanArgs sa;
    sa.Qb = Qbuf; sa.QbT = QbufT;
    sa.Z0 = Z0; sa.Z1 = Z1;
    sa.Y = Y;
    sa.B0 = Bnd0; sa.B1 = Bnd1;
    sa.PW = PW;
    sa.Tb2 = Tb2; sa.Tt2 = Tt2; sa.Tb3 = Tb3; sa.Tt3 = Tt3;
    sa.Tb4 = Tb4; sa.Tt4 = Tt4; sa.Tb5 = Tb5; sa.Tt5 = Tt5;
    sa.Tb6 = Tb6; sa.Tt6 = Tt6;
    sa.Tt0 = Tt0; sa.Tt1 = Tt1; sa.P3T = Pw3T;
    sa.zF = zF;
    void* kargs[] = {(void*)&sa};
    hipError_t ce = hipLaunchCooperativeKernel(
        reinterpret_cast<const void*>(&scan_all), dim3(1024), dim3(256), kargs,
        0, stream);
    if (ce != hipSuccess) {
      // ---- fallback: dispatch-per-stage (round-2 structure) ----
      SqJobs sj[7] = {};
      int nsq[7] = {1, 2, 4, 1, 1, 1, 1};
      sj[0].a[0] = Qbuf;        sj[0].b[0] = QbufT; sj[0].c[0] = PW;          sj[0].ct[0] = Tt0;
      sj[1].a[0] = PW;          sj[1].b[0] = Tt0;   sj[1].c[0] = PW + 2 * M1; sj[1].ct[0] = Tt1;
      sj[1].a[1] = PW;          sj[1].b[1] = QbufT; sj[1].c[1] = PW + 1 * M1; sj[1].ct[1] = Pw3T;
      sj[2].a[0] = PW + 2 * M1; sj[2].b[0] = Tt1;   sj[2].c[0] = Tb2;         sj[2].ct[0] = Tt2;
      sj[2].a[1] = PW + 2 * M1; sj[2].b[1] = QbufT; sj[2].c[1] = PW + 3 * M1;
      sj[2].a[2] = PW + 2 * M1; sj[2].b[2] = Tt0;   sj[2].c[2] = PW + 4 * M1;
      sj[2].a[3] = PW + 2 * M1; sj[2].b[3] = Pw3T;  sj[2].c[3] = PW + 5 * M1;
      sj[3].a[0] = Tb2;         sj[3].b[0] = Tt2;   sj[3].c[0] = Tb3;         sj[3].ct[0] = Tt3;
      sj[4].a[0] = Tb3;         sj[4].b[0] = Tt3;   sj[4].c[0] = Tb4;         sj[4].ct[0] = Tt4;
      sj[5].a[0] = Tb4;         sj[5].b[0] = Tt4;   sj[5].c[0] = Tb5;         sj[5].ct[0] = Tt5;
      sj[6].a[0] = Tb5;         sj[6].b[0] = Tt5;   sj[6].c[0] = Tb6;         sj[6].ct[0] = Tt6;
      for (int j = 1; j <= 6; ++j) {
        const u16* zin = (j & 1) ? Z0 : Z1;
        u16* zout = (j & 1) ? Z1 : Z0;
        gemm_nt<64, 64, 0, 0, 3, 0, 0, 0, 0, 32>
            <<<dim3(32 + 16 * nsq[j - 1], 16), blk, 0, stream>>>(
                zin, 1024, Qbuf, 1024, zout, 1024, 2048, 1024, zF, zB, nullptr,
                Y, Y, nullptr, j + 1, 0, sj[j - 1]);
      }
      gemm_nt<64, 64, 0, 0, 2, 0, 1, 1, 0, 32>
          <<<dim3(48, 16), blk, 0, stream>>>(Z0, 1024, Qbuf, 1024, Bnd0, 1024,
                                             2048, 1024, zF, zB, nullptr, Y,
                                             nullptr, nullptr, 8, 0, sj[6]);
      u16* TbP2[5] = {Tb2, Tb3, Tb4, Tb5, Tb6};
      float* bc = Bnd0;
      float* bn = Bnd1;
      for (int s = 0; s < 5; ++s) {
        if (s < 4)
          gemm_nt<64, 64, 1, 0, 4, 1, 0, 1, 0, 0>
              <<<dim3(33, 16), blk, 0, stream>>>(bc, 1024, TbP2[s], 1024, bn,
                                                 1024, 2056, 1024, zF, zB,
                                                 nullptr, bc, nullptr, nullptr,
                                                 0, 1 << s, J0);
        else
          gemm_nt<64, 64, 1, 0, 6, 1, 0, 1, 0, 0>
              <<<dim3(33, 16), blk, 0, stream>>>(bc, 1024, TbP2[s], 1024, bn,
                                                 1024, 2056, 1024, zF, zB,
                                                 nullptr, bc, Y, Z0, 0, 1 << s,
                                                 J0);
        float* t = bc;
        bc = bn;
        bn = t;
      }
    }

    // phase 3: Y[8c+j] = local(already in Y) + Q^j @ y_{8c}, j=1..7 parallel
    SqJobs cj{};
    cj.a[0] = PW;  // Q^2.. base; z=0 uses Bv (=Q)
    gemm_nt<64, 64, 0, 0, 7, 0, 0, 0, 0, 0>
        <<<dim3(32, 16, 7), blk, 0, stream>>>(Z0, 1024, Qbuf, 1024, Z1, 1024,
                                              2048, 1024, zF, zB, nullptr, Y,
                                              Y, nullptr, 0, 0, cj);
  } else {
    // ---- slow pipeline (small workspace): original serial structure ----
    u16* Tb[7];
    u16* Tt[7];
    for (int i = 0; i < 7; ++i) {
      Tb[i] = (i & 1) ? Mbuf : WxT;
      Tt[i] = (i & 1) ? Pbuf : WyT;
    }
    for (int j = 1; j <= 6; ++j) {
      const u16* zin = (j & 1) ? Z0 : Z1;
      u16* zout = (j & 1) ? Z1 : Z0;
      gemm_nt<64, 64, 0, 0, 2, 0, 0, 0, 0, 0>
          <<<dim3(32, 16), blk, 0, stream>>>(zin, 1024, Qbuf, 1024, zout, 1024,
                                             2048, 1024, zF, zB, nullptr, Y,
                                             nullptr, nullptr, j + 1, 0, J0);
    }
    gemm_nt<64, 64, 0, 0, 2, 0, 1, 1, 0, 0><<<dim3(32, 16), blk, 0, stream>>>(
        Z0, 1024, Qbuf, 1024, Bnd0, 1024, 2048, 1024, zF, zB, nullptr, Y,
        nullptr, nullptr, 8, 0, J0);
    for (int i = 0; i < 3; ++i) {
      const u16* si = (i == 0) ? Qbuf : Tb[i - 1];
      const u16* st = (i == 0) ? QbufT : Tt[i - 1];
      gemm_nt<64, 64, 0, 0, 0, 0, 0, 0, 1, 0>
          <<<dim3(16, 16), blk, 0, stream>>>(si, 1024, st, 1024, Tb[i], 1024,
                                             1024, 1024, zF, zB, nullptr,
                                             nullptr, nullptr, Tt[i], 0, 0,
                                             J0);
    }
    float* bc = Bnd0;
    float* bn = Bnd1;
    for (int s = 0; s < 5; ++s) {
      if (s < 4)
        gemm_nt<64, 64, 1, 0, 4, 1, 0, 1, 0, 0>
            <<<dim3(33, 16), blk, 0, stream>>>(bc, 1024, Tb[s + 2], 1024, bn,
                                               1024, 2056, 1024, zF, zB,
                                               nullptr, bc, nullptr, nullptr,
                                               0, 1 << s, J0);
      else
        gemm_nt<64, 64, 1, 0, 6, 1, 0, 1, 0, 0>
            <<<dim3(33, 16), blk, 0, stream>>>(bc, 1024, Tb[s + 2], 1024, bn,
                                               1024, 2056, 1024, zF, zB,
                                               nullptr, bc, Y, Z0, 0, 1 << s,
                                               J0);
      if (s < 4) {
        int i = s + 3;
        gemm_nt<64, 64, 0, 0, 0, 0, 0, 0, 1, 0>
            <<<dim3(16, 16), blk, 0, stream>>>(Tb[i - 1], 1024, Tt[i - 1],
                                               1024, Tb[i], 1024, 1024, 1024,
                                               zF, zB, nullptr, nullptr,
                                               nullptr, Tt[i], 0, 0, J0);
      }
      float* t = bc;
      bc = bn;
      bn = t;
    }
    for (int j = 0; j <= 7; ++j) {
      const u16* zin = (j & 1) ? Z1 : Z0;
      u16* zout = (j & 1) ? Z0 : Z1;
      gemm_nt<64, 64, 0, 0, 3, 0, 0, 0, 0, 0>
          <<<dim3(32, 16), blk, 0, stream>>>(zin, 1024, Qbuf, 1024, zout, 1024,
                                             2048, 1024, zF, zB, nullptr, Y, Y,
                                             nullptr, j + 1, 0, J0);
    }
  }
}

// Round 4
// 649.098 us; speedup vs baseline: 5.1692x; 5.1692x over previous
//
#include <hip/hip_runtime.h>

typedef unsigned short u16;
typedef unsigned int   u32;
typedef __attribute__((ext_vector_type(8))) short short8;
typedef __attribute__((ext_vector_type(4))) short short4v;
typedef __attribute__((ext_vector_type(4))) float f32x4;

// up to 4 fused 1024x1024 NT products (C=A@B^T, optional C^T) riding along a
// dispatch as blocks x>=SQF; also carries the Q-power base for EPI=7.
struct SqJobs {
  const u16* a[4];
  const u16* b[4];
  u16* c[4];
  u16* ct[4];
};

__device__ __forceinline__ float bf2f(u16 v) {
  u32 x = ((u32)v) << 16;
  return __builtin_bit_cast(float, x);
}
__device__ __forceinline__ u16 f2bf(float f) {
  u32 x = __builtin_bit_cast(u32, f);
  x += 0x7FFFu + ((x >> 16) & 1u);
  return (u16)(x >> 16);
}
// async global->LDS, 16B/lane; LDS dest = wave-uniform base + lane*16
__device__ __forceinline__ void gload_lds16(const u16* g, u16* l) {
  __builtin_amdgcn_global_load_lds(
      (const __attribute__((address_space(1))) u32*)g,
      (__attribute__((address_space(3))) u32*)l, 16, 0, 0);
}

// ---------------------------------------------------------------------------
// NT GEMM: C[m,n] = sum_k A[m,k]*B[n,k]; bf16 MFMA 16x16x32, fp32 accum.
// K-loop schedules:
//  * bf16 x bf16, BM==64 (PIPE3): 3 LDS buffers, depth-2 prefetch, counted
//    s_waitcnt vmcnt(2) + raw s_barrier (never drain mid-loop; T4). The
//    latency-bound 2-blocks/CU scan dispatches live here.
//  * otherwise: 2-buffer dbuf, __syncthreads per step; fp32 operands issue
//    global loads early / ds_write late.
// ADT/BDT: 0 bf16 operand (async global_load_lds), 1 fp32 (reg-convert)
// AMAP: 1 = Bnd shift map (p=row%257; p<shoff -> zero row, else row-shoff)
// EPI : 0 none; 2 +addf[8*row+jp1,n] fp32 guarded; 3 = 2 + write v to
//       Yout[8*row+jp1,n]; 4 +addf[row,n] fp32;
//       5 U-epilogue: +bias[n]; rows t%2048==0 take v=addf[row,n] (x fp32)
//         and also store to Yout[(row>>11)*257*1024+n] (Bnd0 p=0); rows
//         t%8==1 seed aux16[(row>>3),n] (Z0, bf16); fp32 C out
//       6 HS-final: +addf[row,n]; fp32 C out; rows p=row%257<256 also write
//         bf16 v to aux16[((row/257)*256+p),n]; 1<=p<256 also write v to
//         Yout[(b*2048+8p),n]
//       7 correction: j = blockIdx.z+1; B = (j==1 ? Bv : jb.a[0]+(j-2)*1M)
//         (= Q^j); v += addf[8*row+j,n]; write ONLY Yout[8*row+j,n]; no C.
// OMAP: 1 = out row (row>>8)*257 + (row&255) + 1 (Bnd layout)
// COUT: 0 bf16 out, 1 fp32 out.  TRW: 1 = also write bf16 C^T to aux16.
// SQF : >0 = blocks with blockIdx.x>=SQF run ride-along product
//       pi=(bx-SQF)>>4 from jb (16 x-tiles each, grid.y=16 covers n).
// LDS K-chunk swizzle: slot (r,c) holds global chunk c^(r&3); frag read uses
// column q^(lm&3) -> 16-lane quarters spread across all 32 banks.
// ---------------------------------------------------------------------------
template <int BM, int BN, int ADT, int BDT, int EPI, int AMAP, int OMAP,
          int COUT, int TRW, int SQF>
__global__ __launch_bounds__(256) void gemm_nt(
    const void* __restrict__ Av, int lda, const void* __restrict__ Bv, int ldb,
    void* __restrict__ Cv, int ldc, int Mrows, int K,
    const float* __restrict__ zrowF, const u16* __restrict__ zrowB,
    const float* __restrict__ bias, const float* __restrict__ addf,
    float* __restrict__ Yout, u16* __restrict__ aux16, int jp1, int shoff,
    SqJobs jb) {
  constexpr int WM = BM / 2, WN = BN / 2;
  constexpr int MT = WM / 16, NTT = WN / 16;
  constexpr int AIn = ADT ? BM * 8 : BM * 4;  // 16B issues for A tile
  constexpr int BIn = BDT ? BN * 8 : BN * 4;
  static_assert(AIn >= 256 && BIn >= 256, "tile too small for 256 threads");
  constexpr int AI = AIn / 256, BI = BIn / 256;
  constexpr int LA = BM * 32, LB = BN * 32;  // u16 elems per buffer
  constexpr bool PIPE3 = (ADT == 0 && BDT == 0 && BM == 64 && BN == 64);
  constexpr int NBUF = PIPE3 ? 3 : 2;
  __shared__ u16 lA[NBUF * LA];
  __shared__ u16 lB[NBUF * LB];
  const int tid = threadIdx.x;
  const int lane = tid & 63, wid = tid >> 6;
  const int wm = wid & 1, wn = wid >> 1;
  const bool role = (SQF > 0) && ((int)blockIdx.x >= SQF);
  const int pi = role ? (((int)blockIdx.x - SQF) >> 4) : 0;
  const int bxe = role ? (((int)blockIdx.x - SQF) & 15) : (int)blockIdx.x;
  const int m0 = bxe * BM, n0 = blockIdx.y * BN;
  const int effM = role ? 1024 : Mrows;
  const int q = lane >> 4, lm = lane & 15;
  const int cq = (q ^ (lm & 3)) * 8;  // swizzled frag column (u16 units)

  // EPI=7: per-z B operand (Q^j). z=0 -> Bv (=Q); z>=1 -> jb.a[0]+(z-1)*1M.
  const u16* corrB = nullptr;
  if constexpr (EPI == 7)
    corrB = (blockIdx.z == 0)
                ? (const u16*)Bv
                : jb.a[0] + (long)((int)blockIdx.z - 1) * 1048576;

  f32x4 acc[MT][NTT];
#pragma unroll
  for (int mi = 0; mi < MT; ++mi)
#pragma unroll
    for (int ni = 0; ni < NTT; ++ni) acc[mi][ni] = (f32x4){0.f, 0.f, 0.f, 0.f};

  const u16* aB[AI];
  const float* aF[AI];
#pragma unroll
  for (int i = 0; i < AI; ++i) {
    int g = tid + i * 256;
    int r = ADT ? (g >> 3) : (g >> 2);
    int c = ADT ? (g & 7) : (g & 3);
    int row = m0 + r;
    bool valid = (row < effM);
    if (AMAP == 1 && !role) {
      int p = row % 257;
      if (p < shoff) valid = false;
      row -= shoff;
    }
    if constexpr (ADT == 1) {
      int cs = ((((c >> 1) ^ (r & 3)) << 1) | (c & 1)) * 4;
      aF[i] = (valid ? (const float*)Av + (long)row * lda : zrowF) + cs;
    } else {
      int cs = (c ^ (r & 3)) * 8;
      const u16* base;
      if (role)
        base = jb.a[pi] + (long)row * 1024;
      else
        base = valid ? (const u16*)Av + (long)row * lda : zrowB;
      aB[i] = base + cs;
    }
  }
  const u16* bB[BI];
  const float* bF[BI];
#pragma unroll
  for (int i = 0; i < BI; ++i) {
    int g = tid + i * 256;
    int r = BDT ? (g >> 3) : (g >> 2);
    int c = BDT ? (g & 7) : (g & 3);
    if constexpr (BDT == 1) {
      int cs = ((((c >> 1) ^ (r & 3)) << 1) | (c & 1)) * 4;
      bF[i] = (const float*)Bv + (long)(n0 + r) * ldb + cs;
    } else {
      int cs = (c ^ (r & 3)) * 8;
      const u16* base;
      if (role) {
        base = jb.b[pi] + (long)(n0 + r) * 1024;
      } else {
        if constexpr (EPI == 7)
          base = corrB + (long)(n0 + r) * ldb;
        else
          base = (const u16*)Bv + (long)(n0 + r) * ldb;
      }
      bB[i] = base + cs;
    }
  }

  if constexpr (PIPE3) {
    // ---- 3-buffer depth-2 pipeline, counted vmcnt (T4) ----
    static_assert(AI == 1 && BI == 1, "PIPE3 assumes 1+1 issues/thread");
    // prologue: stage 0 -> buf0, stage 1 -> buf1 (4 vmem instr in flight)
    gload_lds16(aB[0], &lA[tid * 8]);
    gload_lds16(bB[0], &lB[tid * 8]);
    gload_lds16(aB[0] + 32, &lA[LA + tid * 8]);
    gload_lds16(bB[0] + 32, &lB[LB + tid * 8]);
    const int NS = K >> 5;
    int cb = 0, pb = 2;  // compute buffer; prefetch buffer = (cb+2)%3
    for (int ks = 0; ks < NS; ++ks) {
      __builtin_amdgcn_sched_barrier(0);  // pin prior ds_read/MFMA before bar
      if (ks + 1 < NS)
        asm volatile("s_waitcnt vmcnt(2)" ::: "memory");  // stage ks done
      else
        asm volatile("s_waitcnt vmcnt(0)" ::: "memory");  // final drain
      __builtin_amdgcn_s_barrier();
      __builtin_amdgcn_sched_barrier(0);  // nothing hoists above barrier
      if (ks + 2 < NS) {  // issue stage ks+2 (stays in flight across bar)
        const int kp = (ks + 2) << 5;
        gload_lds16(aB[0] + kp, &lA[pb * LA + tid * 8]);
        gload_lds16(bB[0] + kp, &lB[pb * LB + tid * 8]);
      }
      const int ca = cb * LA, cbb = cb * LB;
      short8 af[MT], bfr[NTT];
#pragma unroll
      for (int mi = 0; mi < MT; ++mi)
        af[mi] = *(const short8*)&lA[ca + (wm * WM + mi * 16 + lm) * 32 + cq];
#pragma unroll
      for (int ni = 0; ni < NTT; ++ni)
        bfr[ni] =
            *(const short8*)&lB[cbb + (wn * WN + ni * 16 + lm) * 32 + cq];
#pragma unroll
      for (int mi = 0; mi < MT; ++mi)
#pragma unroll
        for (int ni = 0; ni < NTT; ++ni)
          acc[mi][ni] = __builtin_amdgcn_mfma_f32_16x16x32_bf16(
              af[mi], bfr[ni], acc[mi][ni], 0, 0, 0);
      cb = (cb == 2) ? 0 : cb + 1;
      pb = (pb == 2) ? 0 : pb + 1;
    }
  } else {
    // ---- 2-buffer dbuf, __syncthreads per step ----
    // prologue: stage tile 0 into buffer 0
    if constexpr (ADT == 1) {
      f32x4 f0[AI];
#pragma unroll
      for (int i = 0; i < AI; ++i) f0[i] = *(const f32x4*)(aF[i]);
#pragma unroll
      for (int i = 0; i < AI; ++i) {
        short4v s = {(short)f2bf(f0[i][0]), (short)f2bf(f0[i][1]),
                     (short)f2bf(f0[i][2]), (short)f2bf(f0[i][3])};
        *(short4v*)&lA[(tid + i * 256) * 4] = s;
      }
    } else {
#pragma unroll
      for (int i = 0; i < AI; ++i)
        gload_lds16(aB[i], &lA[(tid + i * 256) * 8]);
    }
    if constexpr (BDT == 1) {
      f32x4 f0[BI];
#pragma unroll
      for (int i = 0; i < BI; ++i) f0[i] = *(const f32x4*)(bF[i]);
#pragma unroll
      for (int i = 0; i < BI; ++i) {
        short4v s = {(short)f2bf(f0[i][0]), (short)f2bf(f0[i][1]),
                     (short)f2bf(f0[i][2]), (short)f2bf(f0[i][3])};
        *(short4v*)&lB[(tid + i * 256) * 4] = s;
      }
    } else {
#pragma unroll
      for (int i = 0; i < BI; ++i)
        gload_lds16(bB[i], &lB[(tid + i * 256) * 8]);
    }
    __syncthreads();  // tile 0 staged (vmcnt+lgkm drained)

    int cur = 0;
    for (int k0 = 0; k0 < K; k0 += 32) {
      const int kn = k0 + 32;
      const bool more = kn < K;
      const int nxA = (cur ^ 1) * LA, nxB = (cur ^ 1) * LB;
      f32x4 fa[AI], fb[BI];
      // issue next-tile global loads (stage-early)
      if (more) {
        if constexpr (ADT == 1) {
#pragma unroll
          for (int i = 0; i < AI; ++i) fa[i] = *(const f32x4*)(aF[i] + kn);
        } else {
#pragma unroll
          for (int i = 0; i < AI; ++i)
            gload_lds16(aB[i] + kn, &lA[nxA + (tid + i * 256) * 8]);
        }
        if constexpr (BDT == 1) {
#pragma unroll
          for (int i = 0; i < BI; ++i) fb[i] = *(const f32x4*)(bF[i] + kn);
        } else {
#pragma unroll
          for (int i = 0; i < BI; ++i)
            gload_lds16(bB[i] + kn, &lB[nxB + (tid + i * 256) * 8]);
        }
      }
      // compute current tile (hides the in-flight loads)
      short8 af[MT], bf[NTT];
#pragma unroll
      for (int mi = 0; mi < MT; ++mi)
        af[mi] =
            *(const short8*)&lA[cur * LA + (wm * WM + mi * 16 + lm) * 32 + cq];
#pragma unroll
      for (int ni = 0; ni < NTT; ++ni)
        bf[ni] =
            *(const short8*)&lB[cur * LB + (wn * WN + ni * 16 + lm) * 32 + cq];
#pragma unroll
      for (int mi = 0; mi < MT; ++mi)
#pragma unroll
        for (int ni = 0; ni < NTT; ++ni)
          acc[mi][ni] = __builtin_amdgcn_mfma_f32_16x16x32_bf16(
              af[mi], bf[ni], acc[mi][ni], 0, 0, 0);
      // late convert+ds_write for fp32 operands (vmcnt-wait lands post-MFMA)
      if (more) {
        if constexpr (ADT == 1) {
#pragma unroll
          for (int i = 0; i < AI; ++i) {
            short4v s = {(short)f2bf(fa[i][0]), (short)f2bf(fa[i][1]),
                         (short)f2bf(fa[i][2]), (short)f2bf(fa[i][3])};
            *(short4v*)&lA[nxA + (tid + i * 256) * 4] = s;
          }
        }
        if constexpr (BDT == 1) {
#pragma unroll
          for (int i = 0; i < BI; ++i) {
            short4v s = {(short)f2bf(fb[i][0]), (short)f2bf(fb[i][1]),
                         (short)f2bf(fb[i][2]), (short)f2bf(fb[i][3])};
            *(short4v*)&lB[nxB + (tid + i * 256) * 4] = s;
          }
        }
      }
      __syncthreads();  // next tile ready; current buffer free for overwrite
      cur ^= 1;
    }
  }

#pragma unroll
  for (int mi = 0; mi < MT; ++mi) {
    int rbase = m0 + wm * WM + mi * 16 + q * 4;
#pragma unroll
    for (int ni = 0; ni < NTT; ++ni) {
      int ocol = n0 + wn * WN + ni * 16 + lm;
#pragma unroll
      for (int r = 0; r < 4; ++r) {
        int orow = rbase + r;
        float v = acc[mi][ni][r];
        if (role) {
          if (orow < 1024) {
            u16 ov = f2bf(v);
            jb.c[pi][(long)orow * 1024 + ocol] = ov;
            if (jb.ct[pi]) jb.ct[pi][(long)ocol * 1024 + orow] = ov;
          }
          continue;
        }
        if (orow >= Mrows) continue;
        if constexpr (EPI == 7) {
          long urow = 8L * orow + ((int)blockIdx.z + 1);
          float vv = v + addf[urow * 1024 + ocol];
          Yout[urow * 1024 + ocol] = vv;
          continue;
        }
        if constexpr (EPI == 5) {
          v += bias[ocol];
          bool isT0 = (orow & 2047) == 0;
          if (isT0) v = addf[(long)orow * 1024 + ocol];  // y0 = x[:,0] exact
          ((float*)Cv)[(long)orow * ldc + ocol] = v;
          if (isT0) Yout[((long)(orow >> 11) * 257) * 1024 + ocol] = v;
          if ((orow & 7) == 1)
            aux16[((long)(orow >> 3)) * 1024 + ocol] = f2bf(v);
          continue;
        }
        if constexpr (EPI == 6) {
          v += addf[(long)orow * 1024 + ocol];
          ((float*)Cv)[(long)orow * ldc + ocol] = v;
          int b = orow / 257;
          int pp_ = orow - b * 257;
          if (pp_ < 256)
            aux16[((long)(b * 256 + pp_)) * 1024 + ocol] = f2bf(v);
          if (pp_ >= 1 && pp_ < 256)
            Yout[((long)b * 2048 + 8L * pp_) * 1024 + ocol] = v;
          continue;
        }
        long urow = 0;
        bool uok = true;
        if constexpr (EPI == 2 || EPI == 3) {
          urow = 8L * orow + jp1;
          uok = ((urow & 2047) != 0);  // t==0 (mod L) slot invalid
          if (uok) v += addf[urow * 1024 + ocol];
        }
        if constexpr (EPI == 4) v += addf[(long)orow * 1024 + ocol];
        long wrow = orow;
        if constexpr (OMAP == 1)
          wrow = (long)(orow >> 8) * 257 + (orow & 255) + 1;
        if constexpr (COUT == 1)
          ((float*)Cv)[wrow * (long)ldc + ocol] = v;
        else
          ((u16*)Cv)[wrow * (long)ldc + ocol] = f2bf(v);
        if constexpr (TRW == 1) aux16[(long)ocol * ldc + orow] = f2bf(v);
        if constexpr (EPI == 3) {
          if (uok) Yout[urow * 1024 + ocol] = v;
        }
      }
    }
  }
}

// ---------------------------------------------------------------------------
// helpers
// ---------------------------------------------------------------------------
__global__ void zero_misc(float* zF, u16* zB) {
  for (int i = threadIdx.x; i < 2048; i += 256) {
    zF[i] = 0.f;
    zB[i] = 0;
  }
}
__global__ void xconv(const float* __restrict__ x, u16* __restrict__ xb) {
  long i = (long)blockIdx.x * 256 + threadIdx.x;  // 4 elems/thread
  f32x4 v = ((const f32x4*)x)[i];
  short4v s = {(short)f2bf(v[0]), (short)f2bf(v[1]), (short)f2bf(v[2]),
               (short)f2bf(v[3])};
  ((short4v*)xb)[i] = s;
}
// WxT[d,k] = rc_w[k,d]; WyT[d,k] = rc_w[k,1024+d] + rc_w[k,2048+d]
__global__ void prep_wt(const float* __restrict__ rc_w, u16* __restrict__ WxT,
                        u16* __restrict__ WyT) {
  __shared__ u16 tx[64][65];
  __shared__ u16 ty[64][65];
  int kb = blockIdx.x * 64, db = blockIdx.y * 64;
  for (int i = threadIdx.x; i < 64 * 64; i += 256) {
    int r = i >> 6, c = i & 63;
    long base = (long)(kb + r) * 3072 + db + c;
    tx[r][c] = f2bf(rc_w[base]);
    ty[r][c] = f2bf(rc_w[base + 1024] + rc_w[base + 2048]);
  }
  __syncthreads();
  for (int i = threadIdx.x; i < 64 * 64; i += 256) {
    int r = i >> 6, c = i & 63;
    WxT[(long)(db + r) * 1024 + kb + c] = tx[c][r];
    WyT[(long)(db + r) * 1024 + kb + c] = ty[c][r];
  }
}
__global__ void matvec_c(const u16* __restrict__ M_,
                         const float* __restrict__ rb,
                         float* __restrict__ cvec) {
  int row = blockIdx.x;
  int lane = threadIdx.x;
  float s = 0.f;
  for (int k = lane; k < 1024; k += 64)
    s += bf2f(M_[(long)row * 1024 + k]) * rb[k];
  for (int o = 32; o > 0; o >>= 1) s += __shfl_down(s, o, 64);
  if (lane == 0) cvec[row] = s;
}

// ---------------------------------------------------------------------------
extern "C" void kernel_launch(void* const* d_in, const int* in_sizes, int n_in,
                              void* d_out, int out_size, void* d_ws,
                              size_t ws_size, hipStream_t stream) {
  const float* x = (const float*)d_in[0];
  const float* A_w = (const float*)d_in[1];
  const float* C_w = (const float*)d_in[2];
  const float* rc_w = (const float*)d_in[3];
  const float* rc_b = (const float*)d_in[4];
  float* Y = (float*)d_out;  // fp32 U, then final y (same-element RMW)

  char* ws = (char*)d_ws;
  const long MB = 1 << 20;
  u16* Z0 = (u16*)(ws);                 // 4 MB
  u16* Z1 = (u16*)(ws + 4 * MB);        // 4 MB
  float* Bnd0 = (float*)(ws + 8 * MB);  // 2056*1024*4 (reserve 8.5 MB)
  float* Bnd1 = (float*)(ws + 8 * MB + 8912896);
  char* p = ws + 25 * MB;
  u16* Mbuf = (u16*)p;                       // 2 MB
  u16* WxT = (u16*)(p + 2 * MB);             // 2 MB
  u16* WyT = (u16*)(p + 4 * MB);             // 2 MB
  u16* Pbuf = (u16*)(p + 6 * MB);            // 2 MB
  u16* Qbuf = (u16*)(p + 8 * MB);            // 2 MB
  u16* QbufT = (u16*)(p + 10 * MB);          // 2 MB
  float* cvec = (float*)(p + 12 * MB);       // 4 KB
  float* zF = (float*)(p + 12 * MB + 4096);  // 8 KB zeros
  u16* zB = (u16*)(p + 12 * MB + 12288);     // 4 KB zeros
  u16* xbf = (u16*)(p + 12 * MB + 16384);    // 32 MB: x-bf16, then powers
  const size_t need_fast = (size_t)(25 * MB + 12 * MB + 16384) + 33554432;
  const bool fast = ws_size >= need_fast;

  SqJobs J0{};
  dim3 blk(256);
  zero_misc<<<dim3(1), blk, 0, stream>>>(zF, zB);
  if (fast) xconv<<<dim3(16384), blk, 0, stream>>>(x, xbf);
  prep_wt<<<dim3(16, 16), blk, 0, stream>>>(rc_w, WxT, WyT);

  // M = C_w @ A_w (A symmetric -> NT), both fp32
  gemm_nt<64, 64, 1, 1, 0, 0, 0, 0, 0, 0><<<dim3(16, 16), blk, 0, stream>>>(
      C_w, 1024, A_w, 1024, Mbuf, 1024, 1024, 1024, zF, zB, nullptr, nullptr,
      nullptr, nullptr, 0, 0, J0);
  // Q = M @ Wy (emits Q^T too); P = M @ Wx rides along (blocks x>=16)
  SqJobs sjPQ{};
  sjPQ.a[0] = Mbuf;
  sjPQ.b[0] = WxT;
  sjPQ.c[0] = Pbuf;
  gemm_nt<64, 64, 0, 0, 0, 0, 0, 0, 1, 16><<<dim3(32, 16), blk, 0, stream>>>(
      Mbuf, 1024, WyT, 1024, Qbuf, 1024, 1024, 1024, zF, zB, nullptr, nullptr,
      nullptr, QbufT, 0, 0, sjPQ);
  matvec_c<<<dim3(1024), dim3(64), 0, stream>>>(Mbuf, rc_b, cvec);

  // U[t,:] = x[t,:]@P^T + c -> d_out fp32 (EPI5 also: y0/Bnd0-p0 from x,
  // Z0 seed rows t%8==1)
  if (fast)
    gemm_nt<128, 128, 0, 0, 5, 0, 0, 1, 0, 0>
        <<<dim3(128, 8), blk, 0, stream>>>(xbf, 1024, Pbuf, 1024, Y, 1024,
                                           16384, 1024, zF, zB, cvec, x, Bnd0,
                                           Z0, 0, 0, J0);
  else
    gemm_nt<128, 128, 1, 0, 5, 0, 0, 1, 0, 0>
        <<<dim3(128, 8), blk, 0, stream>>>(x, 1024, Pbuf, 1024, Y, 1024, 16384,
                                           1024, zF, zB, cvec, x, Bnd0, Z0, 0,
                                           0, J0);

  if (fast) {
    // ---- fast pipeline: locals saved to Y in phase 1; phase 3 is ONE
    // ---- dispatch of 7 independent correction GEMMs (Y += Z0 @ Q^j^T).
    const long M1 = 1048576;  // one 1024x1024 bf16 matrix, in u16 elements
    u16* PW = xbf;            // slot j-2 = Q^j, j=2..7
    u16* Tb2 = xbf + 6 * M1;
    u16* Tt2 = xbf + 7 * M1;
    u16* Tb3 = xbf + 8 * M1;
    u16* Tt3 = xbf + 9 * M1;
    u16* Tb4 = xbf + 10 * M1;
    u16* Tt4 = xbf + 11 * M1;
    u16* Tb5 = xbf + 12 * M1;
    u16* Tt5 = xbf + 13 * M1;
    u16* Tb6 = xbf + 14 * M1;
    u16* Tt6 = xbf + 15 * M1;
    u16* Tt0 = Mbuf;
    u16* Tt1 = WxT;
    u16* Pw3T = WyT;

    // ride-along job tables per phase-1 dispatch (j=1..6, then final)
    SqJobs sj[7] = {};
    int nsq[7] = {1, 2, 4, 1, 1, 1, 1};
    sj[0].a[0] = Qbuf;        sj[0].b[0] = QbufT; sj[0].c[0] = PW;          sj[0].ct[0] = Tt0;
    sj[1].a[0] = PW;          sj[1].b[0] = Tt0;   sj[1].c[0] = PW + 2 * M1; sj[1].ct[0] = Tt1;
    sj[1].a[1] = PW;          sj[1].b[1] = QbufT; sj[1].c[1] = PW + 1 * M1; sj[1].ct[1] = Pw3T;
    sj[2].a[0] = PW + 2 * M1; sj[2].b[0] = Tt1;   sj[2].c[0] = Tb2;         sj[2].ct[0] = Tt2;
    sj[2].a[1] = PW + 2 * M1; sj[2].b[1] = QbufT; sj[2].c[1] = PW + 3 * M1;
    sj[2].a[2] = PW + 2 * M1; sj[2].b[2] = Tt0;   sj[2].c[2] = PW + 4 * M1;
    sj[2].a[3] = PW + 2 * M1; sj[2].b[3] = Pw3T;  sj[2].c[3] = PW + 5 * M1;
    sj[3].a[0] = Tb2;         sj[3].b[0] = Tt2;   sj[3].c[0] = Tb3;         sj[3].ct[0] = Tt3;
    sj[4].a[0] = Tb3;         sj[4].b[0] = Tt3;   sj[4].c[0] = Tb4;         sj[4].ct[0] = Tt4;
    sj[5].a[0] = Tb4;         sj[5].b[0] = Tt4;   sj[5].c[0] = Tb5;         sj[5].ct[0] = Tt5;
    sj[6].a[0] = Tb5;         sj[6].b[0] = Tt5;   sj[6].c[0] = Tb6;         sj[6].ct[0] = Tt6;

    // phase 1: local chunk scans; EPI=3 writes each local prefix into Y.
    for (int j = 1; j <= 6; ++j) {
      const u16* zin = (j & 1) ? Z0 : Z1;
      u16* zout = (j & 1) ? Z1 : Z0;
      gemm_nt<64, 64, 0, 0, 3, 0, 0, 0, 0, 32>
          <<<dim3(32 + 16 * nsq[j - 1], 16), blk, 0, stream>>>(
              zin, 1024, Qbuf, 1024, zout, 1024, 2048, 1024, zF, zB, nullptr,
              Y, Y, nullptr, j + 1, 0, sj[j - 1]);
    }
    // local chunk-final states -> Bnd0 (Bnd layout), + Q^128 ride
    gemm_nt<64, 64, 0, 0, 2, 0, 1, 1, 0, 32><<<dim3(48, 16), blk, 0, stream>>>(
        Z0, 1024, Qbuf, 1024, Bnd0, 1024, 2048, 1024, zF, zB, nullptr, Y,
        nullptr, nullptr, 8, 0, sj[6]);

    // phase 2: truncated Hillis-Steele over boundaries; final round emits Z0
    // inits AND the t%8==0 rows of Y.
    u16* TbP2[5] = {Tb2, Tb3, Tb4, Tb5, Tb6};
    float* bc = Bnd0;
    float* bn = Bnd1;
    for (int s = 0; s < 5; ++s) {
      if (s < 4)
        gemm_nt<64, 64, 1, 0, 4, 1, 0, 1, 0, 0>
            <<<dim3(33, 16), blk, 0, stream>>>(bc, 1024, TbP2[s], 1024, bn,
                                               1024, 2056, 1024, zF, zB,
                                               nullptr, bc, nullptr, nullptr,
                                               0, 1 << s, J0);
      else
        gemm_nt<64, 64, 1, 0, 6, 1, 0, 1, 0, 0>
            <<<dim3(33, 16), blk, 0, stream>>>(bc, 1024, TbP2[s], 1024, bn,
                                               1024, 2056, 1024, zF, zB,
                                               nullptr, bc, Y, Z0, 0, 1 << s,
                                               J0);
      float* t = bc;
      bc = bn;
      bn = t;
    }

    // phase 3 (collapsed): Y[8c+j] = local(already in Y) + Q^j @ y_{8c},
    // j=1..7 fully parallel via grid.z. 3584 blocks -> 14 blocks/CU.
    SqJobs cj{};
    cj.a[0] = PW;  // Q^2.. base; z=0 uses Bv (=Q)
    gemm_nt<64, 64, 0, 0, 7, 0, 0, 0, 0, 0>
        <<<dim3(32, 16, 7), blk, 0, stream>>>(Z0, 1024, Qbuf, 1024, Z1, 1024,
                                              2048, 1024, zF, zB, nullptr, Y,
                                              Y, nullptr, 0, 0, cj);
  } else {
    // ---- slow pipeline (small workspace): original serial structure ----
    u16* Tb[7];
    u16* Tt[7];
    for (int i = 0; i < 7; ++i) {
      Tb[i] = (i & 1) ? Mbuf : WxT;
      Tt[i] = (i & 1) ? Pbuf : WyT;
    }
    for (int j = 1; j <= 6; ++j) {
      const u16* zin = (j & 1) ? Z0 : Z1;
      u16* zout = (j & 1) ? Z1 : Z0;
      gemm_nt<64, 64, 0, 0, 2, 0, 0, 0, 0, 0>
          <<<dim3(32, 16), blk, 0, stream>>>(zin, 1024, Qbuf, 1024, zout, 1024,
                                             2048, 1024, zF, zB, nullptr, Y,
                                             nullptr, nullptr, j + 1, 0, J0);
    }
    gemm_nt<64, 64, 0, 0, 2, 0, 1, 1, 0, 0><<<dim3(32, 16), blk, 0, stream>>>(
        Z0, 1024, Qbuf, 1024, Bnd0, 1024, 2048, 1024, zF, zB, nullptr, Y,
        nullptr, nullptr, 8, 0, J0);
    for (int i = 0; i < 3; ++i) {
      const u16* si = (i == 0) ? Qbuf : Tb[i - 1];
      const u16* st = (i == 0) ? QbufT : Tt[i - 1];
      gemm_nt<64, 64, 0, 0, 0, 0, 0, 0, 1, 0>
          <<<dim3(16, 16), blk, 0, stream>>>(si, 1024, st, 1024, Tb[i], 1024,
                                             1024, 1024, zF, zB, nullptr,
                                             nullptr, nullptr, Tt[i], 0, 0,
                                             J0);
    }
    float* bc = Bnd0;
    float* bn = Bnd1;
    for (int s = 0; s < 5; ++s) {
      if (s < 4)
        gemm_nt<64, 64, 1, 0, 4, 1, 0, 1, 0, 0>
            <<<dim3(33, 16), blk, 0, stream>>>(bc, 1024, Tb[s + 2], 1024, bn,
                                               1024, 2056, 1024, zF, zB,
                                               nullptr, bc, nullptr, nullptr,
                                               0, 1 << s, J0);
      else
        gemm_nt<64, 64, 1, 0, 6, 1, 0, 1, 0, 0>
            <<<dim3(33, 16), blk, 0, stream>>>(bc, 1024, Tb[s + 2], 1024, bn,
                                               1024, 2056, 1024, zF, zB,
                                               nullptr, bc, Y, Z0, 0, 1 << s,
                                               J0);
      if (s < 4) {
        int i = s + 3;
        gemm_nt<64, 64, 0, 0, 0, 0, 0, 0, 1, 0>
            <<<dim3(16, 16), blk, 0, stream>>>(Tb[i - 1], 1024, Tt[i - 1],
                                               1024, Tb[i], 1024, 1024, 1024,
                                               zF, zB, nullptr, nullptr,
                                               nullptr, Tt[i], 0, 0, J0);
      }
      float* t = bc;
      bc = bn;
      bn = t;
    }
    for (int j = 0; j <= 7; ++j) {
      const u16* zin = (j & 1) ? Z1 : Z0;
      u16* zout = (j & 1) ? Z0 : Z1;
      gemm_nt<64, 64, 0, 0, 3, 0, 0, 0, 0, 0>
          <<<dim3(32, 16), blk, 0, stream>>>(zin, 1024, Qbuf, 1024, zout, 1024,
                                             2048, 1024, zF, zB, nullptr, Y, Y,
                                             nullptr, j + 1, 0, J0);
    }
  }
}

// Round 6
// 643.540 us; speedup vs baseline: 5.2139x; 1.0086x over previous
//
#include <hip/hip_runtime.h>

typedef unsigned short u16;
typedef unsigned int   u32;
typedef __attribute__((ext_vector_type(8))) short short8;
typedef __attribute__((ext_vector_type(4))) short short4v;
typedef __attribute__((ext_vector_type(4))) float f32x4;

// up to 4 fused 1024x1024 NT products (C=A@B^T, optional C^T) riding along a
// dispatch as blocks x>=SQF; also carries the Q-power base for EPI=7.
struct SqJobs {
  const u16* a[4];
  const u16* b[4];
  u16* c[4];
  u16* ct[4];
};

__device__ __forceinline__ float bf2f(u16 v) {
  u32 x = ((u32)v) << 16;
  return __builtin_bit_cast(float, x);
}
__device__ __forceinline__ u16 f2bf(float f) {
  u32 x = __builtin_bit_cast(u32, f);
  x += 0x7FFFu + ((x >> 16) & 1u);
  return (u16)(x >> 16);
}
// async global->LDS, 16B/lane; LDS dest = wave-uniform base + lane*16
__device__ __forceinline__ void gload_lds16(const u16* g, u16* l) {
  __builtin_amdgcn_global_load_lds(
      (const __attribute__((address_space(1))) u32*)g,
      (__attribute__((address_space(3))) u32*)l, 16, 0, 0);
}

// ---------------------------------------------------------------------------
// NT GEMM: C[m,n] = sum_k A[m,k]*B[n,k]; bf16 MFMA 16x16x32, fp32 accum.
// K-loop schedules:
//  * bf16 x bf16, BM==64 (PIPE3): 3 LDS buffers, depth-2 prefetch, counted
//    s_waitcnt vmcnt(2) + raw s_barrier (never drain mid-loop; T4).
//  * otherwise: 2-buffer dbuf, __syncthreads per step; fp32 operands issue
//    global loads early / ds_write late.
// LDS K-chunk swizzle (r5): slot (r,c) holds global chunk c^((r>>1)&3); frag
// read uses slot q^((lm>>1)&3). Per 16-lane quad this spreads the 16B reads
// over all 8 bank-groups (2 lanes each = 2 beats, the b128 floor); the old
// c^(r&3) form left even/odd lanes on 4 groups (4 beats, ~4 extra cy/read,
// SQ_LDS_BANK_CONFLICT 7.3M on phase-3).
// ADT/BDT: 0 bf16 operand (async global_load_lds), 1 fp32 (reg-convert)
// AMAP: 1 = Bnd shift map (p=row%257; p<shoff -> zero row, else row-shoff)
// EPI : 0 none; 2 +addf[8*row+jp1,n] fp32 guarded; 3 = 2 + write v to
//       Yout[8*row+jp1,n]; 4 +addf[row,n] fp32;
//       5 U-epilogue: +bias[n]; rows t%2048==0 take v=addf[row,n] (x fp32)
//         and also store to Yout[(row>>11)*257*1024+n] (Bnd0 p=0); rows
//         t%8==1 seed aux16[(row>>3),n] (Z0, bf16); fp32 C out
//       6 HS-final: +addf[row,n]; fp32 C out; rows p=row%257<256 also write
//         bf16 v to aux16[((row/257)*256+p),n]; 1<=p<256 also write v to
//         Yout[(b*2048+8p),n]
//       7 correction: j = blockIdx.z+1; B = (j==1 ? Bv : jb.a[0]+(j-2)*1M)
//         (= Q^j); v += addf[8*row+j,n]; write ONLY Yout[8*row+j,n]; no C.
// OMAP: 1 = out row (row>>8)*257 + (row&255) + 1 (Bnd layout)
// COUT: 0 bf16 out, 1 fp32 out.  TRW: 1 = also write bf16 C^T to aux16.
// SQF : >0 = blocks with blockIdx.x>=SQF run ride-along product
//       pi=(bx-SQF)>>4 from jb (16 x-tiles each, grid.y=16 covers n).
// ---------------------------------------------------------------------------
template <int BM, int BN, int ADT, int BDT, int EPI, int AMAP, int OMAP,
          int COUT, int TRW, int SQF>
__global__ __launch_bounds__(256) void gemm_nt(
    const void* __restrict__ Av, int lda, const void* __restrict__ Bv, int ldb,
    void* __restrict__ Cv, int ldc, int Mrows, int K,
    const float* __restrict__ zrowF, const u16* __restrict__ zrowB,
    const float* __restrict__ bias, const float* __restrict__ addf,
    float* __restrict__ Yout, u16* __restrict__ aux16, int jp1, int shoff,
    SqJobs jb) {
  constexpr int WM = BM / 2, WN = BN / 2;
  constexpr int MT = WM / 16, NTT = WN / 16;
  constexpr int AIn = ADT ? BM * 8 : BM * 4;  // 16B issues for A tile
  constexpr int BIn = BDT ? BN * 8 : BN * 4;
  static_assert(AIn >= 256 && BIn >= 256, "tile too small for 256 threads");
  constexpr int AI = AIn / 256, BI = BIn / 256;
  constexpr int LA = BM * 32, LB = BN * 32;  // u16 elems per buffer
  constexpr bool PIPE3 = (ADT == 0 && BDT == 0 && BM == 64 && BN == 64);
  constexpr int NBUF = PIPE3 ? 3 : 2;
  __shared__ u16 lA[NBUF * LA];
  __shared__ u16 lB[NBUF * LB];
  const int tid = threadIdx.x;
  const int lane = tid & 63, wid = tid >> 6;
  const int wm = wid & 1, wn = wid >> 1;
  const bool role = (SQF > 0) && ((int)blockIdx.x >= SQF);
  const int pi = role ? (((int)blockIdx.x - SQF) >> 4) : 0;
  const int bxe = role ? (((int)blockIdx.x - SQF) & 15) : (int)blockIdx.x;
  const int m0 = bxe * BM, n0 = blockIdx.y * BN;
  const int effM = role ? 1024 : Mrows;
  const int q = lane >> 4, lm = lane & 15;
  const int cq = (q ^ ((lm >> 1) & 3)) * 8;  // swizzled frag slot (u16 units)

  // EPI=7: per-z B operand (Q^j). z=0 -> Bv (=Q); z>=1 -> jb.a[0]+(z-1)*1M.
  const u16* corrB = nullptr;
  if constexpr (EPI == 7)
    corrB = (blockIdx.z == 0)
                ? (const u16*)Bv
                : jb.a[0] + (long)((int)blockIdx.z - 1) * 1048576;

  f32x4 acc[MT][NTT];
#pragma unroll
  for (int mi = 0; mi < MT; ++mi)
#pragma unroll
    for (int ni = 0; ni < NTT; ++ni) acc[mi][ni] = (f32x4){0.f, 0.f, 0.f, 0.f};

  const u16* aB[AI];
  const float* aF[AI];
#pragma unroll
  for (int i = 0; i < AI; ++i) {
    int g = tid + i * 256;
    int r = ADT ? (g >> 3) : (g >> 2);
    int c = ADT ? (g & 7) : (g & 3);
    int row = m0 + r;
    bool valid = (row < effM);
    if (AMAP == 1 && !role) {
      int p = row % 257;
      if (p < shoff) valid = false;
      row -= shoff;
    }
    if constexpr (ADT == 1) {
      int cs = ((((c >> 1) ^ ((r >> 1) & 3)) << 1) | (c & 1)) * 4;
      aF[i] = (valid ? (const float*)Av + (long)row * lda : zrowF) + cs;
    } else {
      int cs = (c ^ ((r >> 1) & 3)) * 8;
      const u16* base;
      if (role)
        base = jb.a[pi] + (long)row * 1024;
      else
        base = valid ? (const u16*)Av + (long)row * lda : zrowB;
      aB[i] = base + cs;
    }
  }
  const u16* bB[BI];
  const float* bF[BI];
#pragma unroll
  for (int i = 0; i < BI; ++i) {
    int g = tid + i * 256;
    int r = BDT ? (g >> 3) : (g >> 2);
    int c = BDT ? (g & 7) : (g & 3);
    if constexpr (BDT == 1) {
      int cs = ((((c >> 1) ^ ((r >> 1) & 3)) << 1) | (c & 1)) * 4;
      bF[i] = (const float*)Bv + (long)(n0 + r) * ldb + cs;
    } else {
      int cs = (c ^ ((r >> 1) & 3)) * 8;
      const u16* base;
      if (role) {
        base = jb.b[pi] + (long)(n0 + r) * 1024;
      } else {
        if constexpr (EPI == 7)
          base = corrB + (long)(n0 + r) * ldb;
        else
          base = (const u16*)Bv + (long)(n0 + r) * ldb;
      }
      bB[i] = base + cs;
    }
  }

  if constexpr (PIPE3) {
    // ---- 3-buffer depth-2 pipeline, counted vmcnt (T4) ----
    static_assert(AI == 1 && BI == 1, "PIPE3 assumes 1+1 issues/thread");
    gload_lds16(aB[0], &lA[tid * 8]);
    gload_lds16(bB[0], &lB[tid * 8]);
    gload_lds16(aB[0] + 32, &lA[LA + tid * 8]);
    gload_lds16(bB[0] + 32, &lB[LB + tid * 8]);
    const int NS = K >> 5;
    int cb = 0, pb = 2;  // compute buffer; prefetch buffer = (cb+2)%3
    for (int ks = 0; ks < NS; ++ks) {
      __builtin_amdgcn_sched_barrier(0);  // pin prior ds_read/MFMA before bar
      if (ks + 1 < NS)
        asm volatile("s_waitcnt vmcnt(2)" ::: "memory");  // stage ks done
      else
        asm volatile("s_waitcnt vmcnt(0)" ::: "memory");  // final drain
      __builtin_amdgcn_s_barrier();
      __builtin_amdgcn_sched_barrier(0);  // nothing hoists above barrier
      if (ks + 2 < NS) {  // issue stage ks+2 (stays in flight across bar)
        const int kp = (ks + 2) << 5;
        gload_lds16(aB[0] + kp, &lA[pb * LA + tid * 8]);
        gload_lds16(bB[0] + kp, &lB[pb * LB + tid * 8]);
      }
      const int ca = cb * LA, cbb = cb * LB;
      short8 af[MT], bfr[NTT];
#pragma unroll
      for (int mi = 0; mi < MT; ++mi)
        af[mi] = *(const short8*)&lA[ca + (wm * WM + mi * 16 + lm) * 32 + cq];
#pragma unroll
      for (int ni = 0; ni < NTT; ++ni)
        bfr[ni] =
            *(const short8*)&lB[cbb + (wn * WN + ni * 16 + lm) * 32 + cq];
#pragma unroll
      for (int mi = 0; mi < MT; ++mi)
#pragma unroll
        for (int ni = 0; ni < NTT; ++ni)
          acc[mi][ni] = __builtin_amdgcn_mfma_f32_16x16x32_bf16(
              af[mi], bfr[ni], acc[mi][ni], 0, 0, 0);
      cb = (cb == 2) ? 0 : cb + 1;
      pb = (pb == 2) ? 0 : pb + 1;
    }
  } else {
    // ---- 2-buffer dbuf, __syncthreads per step ----
    if constexpr (ADT == 1) {
      f32x4 f0[AI];
#pragma unroll
      for (int i = 0; i < AI; ++i) f0[i] = *(const f32x4*)(aF[i]);
#pragma unroll
      for (int i = 0; i < AI; ++i) {
        short4v s = {(short)f2bf(f0[i][0]), (short)f2bf(f0[i][1]),
                     (short)f2bf(f0[i][2]), (short)f2bf(f0[i][3])};
        *(short4v*)&lA[(tid + i * 256) * 4] = s;
      }
    } else {
#pragma unroll
      for (int i = 0; i < AI; ++i)
        gload_lds16(aB[i], &lA[(tid + i * 256) * 8]);
    }
    if constexpr (BDT == 1) {
      f32x4 f0[BI];
#pragma unroll
      for (int i = 0; i < BI; ++i) f0[i] = *(const f32x4*)(bF[i]);
#pragma unroll
      for (int i = 0; i < BI; ++i) {
        short4v s = {(short)f2bf(f0[i][0]), (short)f2bf(f0[i][1]),
                     (short)f2bf(f0[i][2]), (short)f2bf(f0[i][3])};
        *(short4v*)&lB[(tid + i * 256) * 4] = s;
      }
    } else {
#pragma unroll
      for (int i = 0; i < BI; ++i)
        gload_lds16(bB[i], &lB[(tid + i * 256) * 8]);
    }
    __syncthreads();  // tile 0 staged (vmcnt+lgkm drained)

    int cur = 0;
    for (int k0 = 0; k0 < K; k0 += 32) {
      const int kn = k0 + 32;
      const bool more = kn < K;
      const int nxA = (cur ^ 1) * LA, nxB = (cur ^ 1) * LB;
      f32x4 fa[AI], fb[BI];
      // issue next-tile global loads (stage-early)
      if (more) {
        if constexpr (ADT == 1) {
#pragma unroll
          for (int i = 0; i < AI; ++i) fa[i] = *(const f32x4*)(aF[i] + kn);
        } else {
#pragma unroll
          for (int i = 0; i < AI; ++i)
            gload_lds16(aB[i] + kn, &lA[nxA + (tid + i * 256) * 8]);
        }
        if constexpr (BDT == 1) {
#pragma unroll
          for (int i = 0; i < BI; ++i) fb[i] = *(const f32x4*)(bF[i] + kn);
        } else {
#pragma unroll
          for (int i = 0; i < BI; ++i)
            gload_lds16(bB[i] + kn, &lB[nxB + (tid + i * 256) * 8]);
        }
      }
      // compute current tile (hides the in-flight loads)
      short8 af[MT], bf[NTT];
#pragma unroll
      for (int mi = 0; mi < MT; ++mi)
        af[mi] =
            *(const short8*)&lA[cur * LA + (wm * WM + mi * 16 + lm) * 32 + cq];
#pragma unroll
      for (int ni = 0; ni < NTT; ++ni)
        bf[ni] =
            *(const short8*)&lB[cur * LB + (wn * WN + ni * 16 + lm) * 32 + cq];
#pragma unroll
      for (int mi = 0; mi < MT; ++mi)
#pragma unroll
        for (int ni = 0; ni < NTT; ++ni)
          acc[mi][ni] = __builtin_amdgcn_mfma_f32_16x16x32_bf16(
              af[mi], bf[ni], acc[mi][ni], 0, 0, 0);
      // late convert+ds_write for fp32 operands (vmcnt-wait lands post-MFMA)
      if (more) {
        if constexpr (ADT == 1) {
#pragma unroll
          for (int i = 0; i < AI; ++i) {
            short4v s = {(short)f2bf(fa[i][0]), (short)f2bf(fa[i][1]),
                         (short)f2bf(fa[i][2]), (short)f2bf(fa[i][3])};
            *(short4v*)&lA[nxA + (tid + i * 256) * 4] = s;
          }
        }
        if constexpr (BDT == 1) {
#pragma unroll
          for (int i = 0; i < BI; ++i) {
            short4v s = {(short)f2bf(fb[i][0]), (short)f2bf(fb[i][1]),
                         (short)f2bf(fb[i][2]), (short)f2bf(fb[i][3])};
            *(short4v*)&lB[nxB + (tid + i * 256) * 4] = s;
          }
        }
      }
      __syncthreads();  // next tile ready; current buffer free for overwrite
      cur ^= 1;
    }
  }

#pragma unroll
  for (int mi = 0; mi < MT; ++mi) {
    int rbase = m0 + wm * WM + mi * 16 + q * 4;
#pragma unroll
    for (int ni = 0; ni < NTT; ++ni) {
      int ocol = n0 + wn * WN + ni * 16 + lm;
#pragma unroll
      for (int r = 0; r < 4; ++r) {
        int orow = rbase + r;
        float v = acc[mi][ni][r];
        if (role) {
          if (orow < 1024) {
            u16 ov = f2bf(v);
            jb.c[pi][(long)orow * 1024 + ocol] = ov;
            if (jb.ct[pi]) jb.ct[pi][(long)ocol * 1024 + orow] = ov;
          }
          continue;
        }
        if (orow >= Mrows) continue;
        if constexpr (EPI == 7) {
          long urow = 8L * orow + ((int)blockIdx.z + 1);
          float vv = v + addf[urow * 1024 + ocol];
          Yout[urow * 1024 + ocol] = vv;
          continue;
        }
        if constexpr (EPI == 5) {
          v += bias[ocol];
          bool isT0 = (orow & 2047) == 0;
          if (isT0) v = addf[(long)orow * 1024 + ocol];  // y0 = x[:,0] exact
          ((float*)Cv)[(long)orow * ldc + ocol] = v;
          if (isT0) Yout[((long)(orow >> 11) * 257) * 1024 + ocol] = v;
          if ((orow & 7) == 1)
            aux16[((long)(orow >> 3)) * 1024 + ocol] = f2bf(v);
          continue;
        }
        if constexpr (EPI == 6) {
          v += addf[(long)orow * 1024 + ocol];
          ((float*)Cv)[(long)orow * ldc + ocol] = v;
          int b = orow / 257;
          int pp_ = orow - b * 257;
          if (pp_ < 256)
            aux16[((long)(b * 256 + pp_)) * 1024 + ocol] = f2bf(v);
          if (pp_ >= 1 && pp_ < 256)
            Yout[((long)b * 2048 + 8L * pp_) * 1024 + ocol] = v;
          continue;
        }
        long urow = 0;
        bool uok = true;
        if constexpr (EPI == 2 || EPI == 3) {
          urow = 8L * orow + jp1;
          uok = ((urow & 2047) != 0);  // t==0 (mod L) slot invalid
          if (uok) v += addf[urow * 1024 + ocol];
        }
        if constexpr (EPI == 4) v += addf[(long)orow * 1024 + ocol];
        long wrow = orow;
        if constexpr (OMAP == 1)
          wrow = (long)(orow >> 8) * 257 + (orow & 255) + 1;
        if constexpr (COUT == 1)
          ((float*)Cv)[wrow * (long)ldc + ocol] = v;
        else
          ((u16*)Cv)[wrow * (long)ldc + ocol] = f2bf(v);
        if constexpr (TRW == 1) aux16[(long)ocol * ldc + orow] = f2bf(v);
        if constexpr (EPI == 3) {
          if (uok) Yout[urow * 1024 + ocol] = v;
        }
      }
    }
  }
}

// ---------------------------------------------------------------------------
// helpers
// ---------------------------------------------------------------------------
__global__ void zero_misc(float* zF, u16* zB) {
  for (int i = threadIdx.x; i < 2048; i += 256) {
    zF[i] = 0.f;
    zB[i] = 0;
  }
}
__global__ void xconv(const float* __restrict__ x, u16* __restrict__ xb) {
  long i = (long)blockIdx.x * 256 + threadIdx.x;  // 4 elems/thread
  f32x4 v = ((const f32x4*)x)[i];
  short4v s = {(short)f2bf(v[0]), (short)f2bf(v[1]), (short)f2bf(v[2]),
               (short)f2bf(v[3])};
  ((short4v*)xb)[i] = s;
}
// WxT[d,k] = rc_w[k,d]; WyT[d,k] = rc_w[k,1024+d] + rc_w[k,2048+d]
__global__ void prep_wt(const float* __restrict__ rc_w, u16* __restrict__ WxT,
                        u16* __restrict__ WyT) {
  __shared__ u16 tx[64][65];
  __shared__ u16 ty[64][65];
  int kb = blockIdx.x * 64, db = blockIdx.y * 64;
  for (int i = threadIdx.x; i < 64 * 64; i += 256) {
    int r = i >> 6, c = i & 63;
    long base = (long)(kb + r) * 3072 + db + c;
    tx[r][c] = f2bf(rc_w[base]);
    ty[r][c] = f2bf(rc_w[base + 1024] + rc_w[base + 2048]);
  }
  __syncthreads();
  for (int i = threadIdx.x; i < 64 * 64; i += 256) {
    int r = i >> 6, c = i & 63;
    WxT[(long)(db + r) * 1024 + kb + c] = tx[c][r];
    WyT[(long)(db + r) * 1024 + kb + c] = ty[c][r];
  }
}
__global__ void matvec_c(const u16* __restrict__ M_,
                         const float* __restrict__ rb,
                         float* __restrict__ cvec) {
  int row = blockIdx.x;
  int lane = threadIdx.x;
  float s = 0.f;
  for (int k = lane; k < 1024; k += 64)
    s += bf2f(M_[(long)row * 1024 + k]) * rb[k];
  for (int o = 32; o > 0; o >>= 1) s += __shfl_down(s, o, 64);
  if (lane == 0) cvec[row] = s;
}

// ---------------------------------------------------------------------------
extern "C" void kernel_launch(void* const* d_in, const int* in_sizes, int n_in,
                              void* d_out, int out_size, void* d_ws,
                              size_t ws_size, hipStream_t stream) {
  const float* x = (const float*)d_in[0];
  const float* A_w = (const float*)d_in[1];
  const float* C_w = (const float*)d_in[2];
  const float* rc_w = (const float*)d_in[3];
  const float* rc_b = (const float*)d_in[4];
  float* Y = (float*)d_out;  // fp32 U, then final y (same-element RMW)

  char* ws = (char*)d_ws;
  const long MB = 1 << 20;
  u16* Z0 = (u16*)(ws);                 // 4 MB
  u16* Z1 = (u16*)(ws + 4 * MB);        // 4 MB
  float* Bnd0 = (float*)(ws + 8 * MB);  // 2056*1024*4 (reserve 8.5 MB)
  float* Bnd1 = (float*)(ws + 8 * MB + 8912896);
  char* p = ws + 25 * MB;
  u16* Mbuf = (u16*)p;                       // 2 MB
  u16* WxT = (u16*)(p + 2 * MB);             // 2 MB
  u16* WyT = (u16*)(p + 4 * MB);             // 2 MB
  u16* Pbuf = (u16*)(p + 6 * MB);            // 2 MB
  u16* Qbuf = (u16*)(p + 8 * MB);            // 2 MB
  u16* QbufT = (u16*)(p + 10 * MB);          // 2 MB
  float* cvec = (float*)(p + 12 * MB);       // 4 KB
  float* zF = (float*)(p + 12 * MB + 4096);  // 8 KB zeros
  u16* zB = (u16*)(p + 12 * MB + 12288);     // 4 KB zeros
  u16* xbf = (u16*)(p + 12 * MB + 16384);    // 32 MB: x-bf16, then powers
  const size_t need_fast = (size_t)(25 * MB + 12 * MB + 16384) + 33554432;
  const bool fast = ws_size >= need_fast;

  SqJobs J0{};
  dim3 blk(256);
  zero_misc<<<dim3(1), blk, 0, stream>>>(zF, zB);
  if (fast) xconv<<<dim3(16384), blk, 0, stream>>>(x, xbf);
  prep_wt<<<dim3(16, 16), blk, 0, stream>>>(rc_w, WxT, WyT);

  // M = C_w @ A_w (A symmetric -> NT), both fp32
  gemm_nt<64, 64, 1, 1, 0, 0, 0, 0, 0, 0><<<dim3(16, 16), blk, 0, stream>>>(
      C_w, 1024, A_w, 1024, Mbuf, 1024, 1024, 1024, zF, zB, nullptr, nullptr,
      nullptr, nullptr, 0, 0, J0);
  // Q = M @ Wy (emits Q^T too); P = M @ Wx rides along (blocks x>=16)
  SqJobs sjPQ{};
  sjPQ.a[0] = Mbuf;
  sjPQ.b[0] = WxT;
  sjPQ.c[0] = Pbuf;
  gemm_nt<64, 64, 0, 0, 0, 0, 0, 0, 1, 16><<<dim3(32, 16), blk, 0, stream>>>(
      Mbuf, 1024, WyT, 1024, Qbuf, 1024, 1024, 1024, zF, zB, nullptr, nullptr,
      nullptr, QbufT, 0, 0, sjPQ);
  matvec_c<<<dim3(1024), dim3(64), 0, stream>>>(Mbuf, rc_b, cvec);

  // U[t,:] = x[t,:]@P^T + c -> d_out fp32 (EPI5 also: y0/Bnd0-p0 from x,
  // Z0 seed rows t%8==1)
  if (fast)
    gemm_nt<128, 128, 0, 0, 5, 0, 0, 1, 0, 0>
        <<<dim3(128, 8), blk, 0, stream>>>(xbf, 1024, Pbuf, 1024, Y, 1024,
                                           16384, 1024, zF, zB, cvec, x, Bnd0,
                                           Z0, 0, 0, J0);
  else
    gemm_nt<128, 128, 1, 0, 5, 0, 0, 1, 0, 0>
        <<<dim3(128, 8), blk, 0, stream>>>(x, 1024, Pbuf, 1024, Y, 1024, 16384,
                                           1024, zF, zB, cvec, x, Bnd0, Z0, 0,
                                           0, J0);

  if (fast) {
    // ---- fast pipeline: locals saved to Y in phase 1; phase 3 is ONE
    // ---- dispatch of 7 independent correction GEMMs (Y += Z0 @ Q^j^T).
    const long M1 = 1048576;  // one 1024x1024 bf16 matrix, in u16 elements
    u16* PW = xbf;            // slot j-2 = Q^j, j=2..7
    u16* Tb2 = xbf + 6 * M1;
    u16* Tt2 = xbf + 7 * M1;
    u16* Tb3 = xbf + 8 * M1;
    u16* Tt3 = xbf + 9 * M1;
    u16* Tb4 = xbf + 10 * M1;
    u16* Tt4 = xbf + 11 * M1;
    u16* Tb5 = xbf + 12 * M1;
    u16* Tt5 = xbf + 13 * M1;
    u16* Tb6 = xbf + 14 * M1;
    u16* Tt6 = xbf + 15 * M1;
    u16* Tt0 = Mbuf;
    u16* Tt1 = WxT;
    u16* Pw3T = WyT;

    // ride-along job tables per phase-1 dispatch (j=1..6, then final)
    SqJobs sj[7] = {};
    int nsq[7] = {1, 2, 4, 1, 1, 1, 1};
    sj[0].a[0] = Qbuf;        sj[0].b[0] = QbufT; sj[0].c[0] = PW;          sj[0].ct[0] = Tt0;
    sj[1].a[0] = PW;          sj[1].b[0] = Tt0;   sj[1].c[0] = PW + 2 * M1; sj[1].ct[0] = Tt1;
    sj[1].a[1] = PW;          sj[1].b[1] = QbufT; sj[1].c[1] = PW + 1 * M1; sj[1].ct[1] = Pw3T;
    sj[2].a[0] = PW + 2 * M1; sj[2].b[0] = Tt1;   sj[2].c[0] = Tb2;         sj[2].ct[0] = Tt2;
    sj[2].a[1] = PW + 2 * M1; sj[2].b[1] = QbufT; sj[2].c[1] = PW + 3 * M1;
    sj[2].a[2] = PW + 2 * M1; sj[2].b[2] = Tt0;   sj[2].c[2] = PW + 4 * M1;
    sj[2].a[3] = PW + 2 * M1; sj[2].b[3] = Pw3T;  sj[2].c[3] = PW + 5 * M1;
    sj[3].a[0] = Tb2;         sj[3].b[0] = Tt2;   sj[3].c[0] = Tb3;         sj[3].ct[0] = Tt3;
    sj[4].a[0] = Tb3;         sj[4].b[0] = Tt3;   sj[4].c[0] = Tb4;         sj[4].ct[0] = Tt4;
    sj[5].a[0] = Tb4;         sj[5].b[0] = Tt4;   sj[5].c[0] = Tb5;         sj[5].ct[0] = Tt5;
    sj[6].a[0] = Tb5;         sj[6].b[0] = Tt5;   sj[6].c[0] = Tb6;         sj[6].ct[0] = Tt6;

    // phase 1: local chunk scans; EPI=3 writes each local prefix into Y.
    for (int j = 1; j <= 6; ++j) {
      const u16* zin = (j & 1) ? Z0 : Z1;
      u16* zout = (j & 1) ? Z1 : Z0;
      gemm_nt<64, 64, 0, 0, 3, 0, 0, 0, 0, 32>
          <<<dim3(32 + 16 * nsq[j - 1], 16), blk, 0, stream>>>(
              zin, 1024, Qbuf, 1024, zout, 1024, 2048, 1024, zF, zB, nullptr,
              Y, Y, nullptr, j + 1, 0, sj[j - 1]);
    }
    // local chunk-final states -> Bnd0 (Bnd layout), + Q^128 ride
    gemm_nt<64, 64, 0, 0, 2, 0, 1, 1, 0, 32><<<dim3(48, 16), blk, 0, stream>>>(
        Z0, 1024, Qbuf, 1024, Bnd0, 1024, 2048, 1024, zF, zB, nullptr, Y,
        nullptr, nullptr, 8, 0, sj[6]);

    // phase 2: truncated Hillis-Steele over boundaries; final round emits Z0
    // inits AND the t%8==0 rows of Y.
    u16* TbP2[5] = {Tb2, Tb3, Tb4, Tb5, Tb6};
    float* bc = Bnd0;
    float* bn = Bnd1;
    for (int s = 0; s < 5; ++s) {
      if (s < 4)
        gemm_nt<64, 64, 1, 0, 4, 1, 0, 1, 0, 0>
            <<<dim3(33, 16), blk, 0, stream>>>(bc, 1024, TbP2[s], 1024, bn,
                                               1024, 2056, 1024, zF, zB,
                                               nullptr, bc, nullptr, nullptr,
                                               0, 1 << s, J0);
      else
        gemm_nt<64, 64, 1, 0, 6, 1, 0, 1, 0, 0>
            <<<dim3(33, 16), blk, 0, stream>>>(bc, 1024, TbP2[s], 1024, bn,
                                               1024, 2056, 1024, zF, zB,
                                               nullptr, bc, Y, Z0, 0, 1 << s,
                                               J0);
      float* t = bc;
      bc = bn;
      bn = t;
    }

    // phase 3 (collapsed): Y[8c+j] = local(already in Y) + Q^j @ y_{8c},
    // j=1..7 fully parallel via grid.z. 3584 blocks -> 14 blocks/CU.
    SqJobs cj{};
    cj.a[0] = PW;  // Q^2.. base; z=0 uses Bv (=Q)
    gemm_nt<64, 64, 0, 0, 7, 0, 0, 0, 0, 0>
        <<<dim3(32, 16, 7), blk, 0, stream>>>(Z0, 1024, Qbuf, 1024, Z1, 1024,
                                              2048, 1024, zF, zB, nullptr, Y,
                                              Y, nullptr, 0, 0, cj);
  } else {
    // ---- slow pipeline (small workspace): original serial structure ----
    u16* Tb[7];
    u16* Tt[7];
    for (int i = 0; i < 7; ++i) {
      Tb[i] = (i & 1) ? Mbuf : WxT;
      Tt[i] = (i & 1) ? Pbuf : WyT;
    }
    for (int j = 1; j <= 6; ++j) {
      const u16* zin = (j & 1) ? Z0 : Z1;
      u16* zout = (j & 1) ? Z1 : Z0;
      gemm_nt<64, 64, 0, 0, 2, 0, 0, 0, 0, 0>
          <<<dim3(32, 16), blk, 0, stream>>>(zin, 1024, Qbuf, 1024, zout, 1024,
                                             2048, 1024, zF, zB, nullptr, Y,
                                             nullptr, nullptr, j + 1, 0, J0);
    }
    gemm_nt<64, 64, 0, 0, 2, 0, 1, 1, 0, 0><<<dim3(32, 16), blk, 0, stream>>>(
        Z0, 1024, Qbuf, 1024, Bnd0, 1024, 2048, 1024, zF, zB, nullptr, Y,
        nullptr, nullptr, 8, 0, J0);
    for (int i = 0; i < 3; ++i) {
      const u16* si = (i == 0) ? Qbuf : Tb[i - 1];
      const u16* st = (i == 0) ? QbufT : Tt[i - 1];
      gemm_nt<64, 64, 0, 0, 0, 0, 0, 0, 1, 0>
          <<<dim3(16, 16), blk, 0, stream>>>(si, 1024, st, 1024, Tb[i], 1024,
                                             1024, 1024, zF, zB, nullptr,
                                             nullptr, nullptr, Tt[i], 0, 0,
                                             J0);
    }
    float* bc = Bnd0;
    float* bn = Bnd1;
    for (int s = 0; s < 5; ++s) {
      if (s < 4)
        gemm_nt<64, 64, 1, 0, 4, 1, 0, 1, 0, 0>
            <<<dim3(33, 16), blk, 0, stream>>>(bc, 1024, Tb[s + 2], 1024, bn,
                                               1024, 2056, 1024, zF, zB,
                                               nullptr, bc, nullptr, nullptr,
                                               0, 1 << s, J0);
      else
        gemm_nt<64, 64, 1, 0, 6, 1, 0, 1, 0, 0>
            <<<dim3(33, 16), blk, 0, stream>>>(bc, 1024, Tb[s + 2], 1024, bn,
                                               1024, 2056, 1024, zF, zB,
                                               nullptr, bc, Y, Z0, 0, 1 << s,
                                               J0);
      if (s < 4) {
        int i = s + 3;
        gemm_nt<64, 64, 0, 0, 0, 0, 0, 0, 1, 0>
            <<<dim3(16, 16), blk, 0, stream>>>(Tb[i - 1], 1024, Tt[i - 1],
                                               1024, Tb[i], 1024, 1024, 1024,
                                               zF, zB, nullptr, nullptr,
                                               nullptr, Tt[i], 0, 0, J0);
      }
      float* t = bc;
      bc = bn;
      bn = t;
    }
    for (int j = 0; j <= 7; ++j) {
      const u16* zin = (j & 1) ? Z1 : Z0;
      u16* zout = (j & 1) ? Z0 : Z1;
      gemm_nt<64, 64, 0, 0, 3, 0, 0, 0, 0, 0>
          <<<dim3(32, 16), blk, 0, stream>>>(zin, 1024, Qbuf, 1024, zout, 1024,
                                             2048, 1024, zF, zB, nullptr, Y, Y,
                                             nullptr, j + 1, 0, J0);
    }
  }
}

// Round 7
// 626.543 us; speedup vs baseline: 5.3553x; 1.0271x over previous
//
#include <hip/hip_runtime.h>

typedef unsigned short u16;
typedef unsigned int   u32;
typedef __attribute__((ext_vector_type(8))) short short8;
typedef __attribute__((ext_vector_type(4))) short short4v;
typedef __attribute__((ext_vector_type(4))) float f32x4;

// up to 4 fused 1024x1024 NT products (C=A@B^T, optional C^T) riding along a
// dispatch as blocks x>=SQF; also carries the Q-power base for EPI=7 and the
// XTRA-ride pointers in slot 3.
struct SqJobs {
  const u16* a[4];
  const u16* b[4];
  u16* c[4];
  u16* ct[4];
};

__device__ __forceinline__ float bf2f(u16 v) {
  u32 x = ((u32)v) << 16;
  return __builtin_bit_cast(float, x);
}
__device__ __forceinline__ u16 f2bf(float f) {
  u32 x = __builtin_bit_cast(u32, f);
  x += 0x7FFFu + ((x >> 16) & 1u);
  return (u16)(x >> 16);
}
// async global->LDS, 16B/lane; LDS dest = wave-uniform base + lane*16
__device__ __forceinline__ void gload_lds16(const u16* g, u16* l) {
  __builtin_amdgcn_global_load_lds(
      (const __attribute__((address_space(1))) u32*)g,
      (__attribute__((address_space(3))) u32*)l, 16, 0, 0);
}

// ---------------------------------------------------------------------------
// NT GEMM: C[m,n] = sum_k A[m,k]*B[n,k]; bf16 MFMA 16x16x32, fp32 accum.
// K-loop schedules:
//  * bf16 x bf16, BM==64 (PIPE3): 3 LDS buffers, depth-2 prefetch, counted
//    s_waitcnt vmcnt(2) + raw s_barrier (never drain mid-loop; T4).
//  * otherwise: 2-buffer dbuf, __syncthreads per step; fp32 operands issue
//    global loads early / ds_write late.
// LDS K-chunk swizzle (r5): slot (r,c) holds global chunk c^((r>>1)&3); frag
// read uses slot q^((lm>>1)&3) -> conflict-free ds_read_b128 (r6: verified
// SQ_LDS_BANK_CONFLICT 7.3M -> 0).
// ADT/BDT: 0 bf16 operand (async global_load_lds), 1 fp32 (reg-convert)
// AMAP: 1 = Bnd shift map (p=row%257; p<shoff -> zero row, else row-shoff)
// EPI : 0 none; 2 +addf[8*row+jp1,n] fp32 guarded; 3 = 2 + write v to
//       Yout[8*row+jp1,n]; 4 +addf[row,n] fp32;
//       5 U-epilogue: +bias[n]; rows t%2048==0 take v=addf[row,n] (x fp32)
//         and also store to Yout[(row>>11)*257*1024+n] (Bnd0 p=0); rows
//         t%8==1 seed aux16[(row>>3),n] (Z0, bf16); fp32 C out
//       6 HS-final: +addf[row,n]; fp32 C out; rows p=row%257<256 also write
//         bf16 v to aux16[((row/257)*256+p),n]; 1<=p<256 also write v to
//         Yout[(b*2048+8p),n]
//       7 correction: plane zpl (XCD-pinned remap of grid(32,16,7): lin%8<7
//         works plane lin%8 only -> its Q^j stays L2-resident; XCD 7 takes
//         the remainders); B = (zpl==0 ? Bv : jb.a[0]+(zpl-1)*1M) (= Q^j);
//         v += addf[8*row+j,n]; write ONLY Yout[8*row+j,n]; no C.
// OMAP: 1 = out row (row>>8)*257 + (row&255) + 1 (Bnd layout)
// COUT: 0 bf16 out, 1 fp32 out.  TRW: 1 = also write bf16 C^T to aux16.
// SQF : >0 = blocks with blockIdx.x>=SQF run ride-along product
//       pi=(bx-SQF)>>4 from jb (16 x-tiles each, grid.y=16 covers n).
// XTRA: 1 = blocks bx>=16 run xconv (f32->bf16 x-copy; src=jb.a[3],
//       dst=jb.c[3]; 1024 blocks x 16 f32x4/thread). 2 = blocks bx>=32 run
//       matvec cvec[row]=sum_k bf16(Av[row,k])*rc_b[k] (rb=jb.b[3],
//       cvec=jb.ct[3]; 256 blocks x 4 rows). Fills idle CUs of tiny GEMMs.
// ---------------------------------------------------------------------------
template <int BM, int BN, int ADT, int BDT, int EPI, int AMAP, int OMAP,
          int COUT, int TRW, int SQF, int XTRA>
__global__ __launch_bounds__(256) void gemm_nt(
    const void* __restrict__ Av, int lda, const void* __restrict__ Bv, int ldb,
    void* __restrict__ Cv, int ldc, int Mrows, int K,
    const float* __restrict__ zrowF, const u16* __restrict__ zrowB,
    const float* __restrict__ bias, const float* __restrict__ addf,
    float* __restrict__ Yout, u16* __restrict__ aux16, int jp1, int shoff,
    SqJobs jb) {
  if constexpr (XTRA == 1) {  // xconv ride
    if ((int)blockIdx.x >= 16) {
      const f32x4* xs = (const f32x4*)jb.a[3];
      short4v* xd = (short4v*)jb.c[3];
      const long id = ((long)blockIdx.x - 16) * 16 + blockIdx.y;
      const long base = id * 4096 + threadIdx.x;
#pragma unroll
      for (int k = 0; k < 16; ++k) {
        f32x4 v = xs[base + k * 256];
        short4v s = {(short)f2bf(v[0]), (short)f2bf(v[1]), (short)f2bf(v[2]),
                     (short)f2bf(v[3])};
        xd[base + k * 256] = s;
      }
      return;
    }
  }
  if constexpr (XTRA == 2) {  // matvec ride (cvec = bf16(Av) @ rc_b)
    if ((int)blockIdx.x >= 32) {
      const u16* Mb = (const u16*)Av;
      const float* rb = (const float*)jb.b[3];
      float* cv = (float*)jb.ct[3];
      int row = (((int)blockIdx.x - 32) * 16 + (int)blockIdx.y) * 4 +
                ((int)threadIdx.x >> 6);
      int ln = threadIdx.x & 63;
      float s = 0.f;
      for (int k = ln; k < 1024; k += 64)
        s += bf2f(Mb[(long)row * 1024 + k]) * rb[k];
      for (int o = 32; o > 0; o >>= 1) s += __shfl_down(s, o, 64);
      if (ln == 0) cv[row] = s;
      return;
    }
  }
  constexpr int WM = BM / 2, WN = BN / 2;
  constexpr int MT = WM / 16, NTT = WN / 16;
  constexpr int AIn = ADT ? BM * 8 : BM * 4;  // 16B issues for A tile
  constexpr int BIn = BDT ? BN * 8 : BN * 4;
  static_assert(AIn >= 256 && BIn >= 256, "tile too small for 256 threads");
  constexpr int AI = AIn / 256, BI = BIn / 256;
  constexpr int LA = BM * 32, LB = BN * 32;  // u16 elems per buffer
  constexpr bool PIPE3 = (ADT == 0 && BDT == 0 && BM == 64 && BN == 64);
  constexpr int NBUF = PIPE3 ? 3 : 2;
  __shared__ u16 lA[NBUF * LA];
  __shared__ u16 lB[NBUF * LB];
  const int tid = threadIdx.x;
  const int lane = tid & 63, wid = tid >> 6;
  const int wm = wid & 1, wn = wid >> 1;
  const bool role = (SQF > 0) && ((int)blockIdx.x >= SQF);
  const int pi = role ? (((int)blockIdx.x - SQF) >> 4) : 0;
  const int bxe = role ? (((int)blockIdx.x - SQF) & 15) : (int)blockIdx.x;
  int m0 = bxe * BM, n0 = blockIdx.y * BN;
  int zpl = (int)blockIdx.z;
  if constexpr (EPI == 7) {
    // XCD-pinned plane remap (grid fixed at (32,16,7); lin%8 = XCD).
    int lin = (int)blockIdx.x + 32 * (int)blockIdx.y + 512 * (int)blockIdx.z;
    int xcd = lin & 7, loc = lin >> 3;
    int t;
    if (xcd < 7) {
      zpl = xcd;
      t = loc;
    } else {
      zpl = loc >> 6;
      t = 448 + (loc & 63);
    }
    m0 = (t >> 4) * 64;
    n0 = (t & 15) * 64;
  }
  const int effM = role ? 1024 : Mrows;
  const int q = lane >> 4, lm = lane & 15;
  const int cq = (q ^ ((lm >> 1) & 3)) * 8;  // swizzled frag slot (u16 units)

  // EPI=7: per-plane B operand (Q^j). zpl=0 -> Bv (=Q); else jb.a[0]+...
  const u16* corrB = nullptr;
  if constexpr (EPI == 7)
    corrB = (zpl == 0) ? (const u16*)Bv : jb.a[0] + (long)(zpl - 1) * 1048576;

  f32x4 acc[MT][NTT];
#pragma unroll
  for (int mi = 0; mi < MT; ++mi)
#pragma unroll
    for (int ni = 0; ni < NTT; ++ni) acc[mi][ni] = (f32x4){0.f, 0.f, 0.f, 0.f};

  const u16* aB[AI];
  const float* aF[AI];
#pragma unroll
  for (int i = 0; i < AI; ++i) {
    int g = tid + i * 256;
    int r = ADT ? (g >> 3) : (g >> 2);
    int c = ADT ? (g & 7) : (g & 3);
    int row = m0 + r;
    bool valid = (row < effM);
    if (AMAP == 1 && !role) {
      int p = row % 257;
      if (p < shoff) valid = false;
      row -= shoff;
    }
    if constexpr (ADT == 1) {
      int cs = ((((c >> 1) ^ ((r >> 1) & 3)) << 1) | (c & 1)) * 4;
      aF[i] = (valid ? (const float*)Av + (long)row * lda : zrowF) + cs;
    } else {
      int cs = (c ^ ((r >> 1) & 3)) * 8;
      const u16* base;
      if (role)
        base = jb.a[pi] + (long)row * 1024;
      else
        base = valid ? (const u16*)Av + (long)row * lda : zrowB;
      aB[i] = base + cs;
    }
  }
  const u16* bB[BI];
  const float* bF[BI];
#pragma unroll
  for (int i = 0; i < BI; ++i) {
    int g = tid + i * 256;
    int r = BDT ? (g >> 3) : (g >> 2);
    int c = BDT ? (g & 7) : (g & 3);
    if constexpr (BDT == 1) {
      int cs = ((((c >> 1) ^ ((r >> 1) & 3)) << 1) | (c & 1)) * 4;
      bF[i] = (const float*)Bv + (long)(n0 + r) * ldb + cs;
    } else {
      int cs = (c ^ ((r >> 1) & 3)) * 8;
      const u16* base;
      if (role) {
        base = jb.b[pi] + (long)(n0 + r) * 1024;
      } else {
        if constexpr (EPI == 7)
          base = corrB + (long)(n0 + r) * ldb;
        else
          base = (const u16*)Bv + (long)(n0 + r) * ldb;
      }
      bB[i] = base + cs;
    }
  }

  if constexpr (PIPE3) {
    // ---- 3-buffer depth-2 pipeline, counted vmcnt (T4) ----
    static_assert(AI == 1 && BI == 1, "PIPE3 assumes 1+1 issues/thread");
    gload_lds16(aB[0], &lA[tid * 8]);
    gload_lds16(bB[0], &lB[tid * 8]);
    gload_lds16(aB[0] + 32, &lA[LA + tid * 8]);
    gload_lds16(bB[0] + 32, &lB[LB + tid * 8]);
    const int NS = K >> 5;
    int cb = 0, pb = 2;  // compute buffer; prefetch buffer = (cb+2)%3
    for (int ks = 0; ks < NS; ++ks) {
      __builtin_amdgcn_sched_barrier(0);  // pin prior ds_read/MFMA before bar
      if (ks + 1 < NS)
        asm volatile("s_waitcnt vmcnt(2)" ::: "memory");  // stage ks done
      else
        asm volatile("s_waitcnt vmcnt(0)" ::: "memory");  // final drain
      __builtin_amdgcn_s_barrier();
      __builtin_amdgcn_sched_barrier(0);  // nothing hoists above barrier
      if (ks + 2 < NS) {  // issue stage ks+2 (stays in flight across bar)
        const int kp = (ks + 2) << 5;
        gload_lds16(aB[0] + kp, &lA[pb * LA + tid * 8]);
        gload_lds16(bB[0] + kp, &lB[pb * LB + tid * 8]);
      }
      const int ca = cb * LA, cbb = cb * LB;
      short8 af[MT], bfr[NTT];
#pragma unroll
      for (int mi = 0; mi < MT; ++mi)
        af[mi] = *(const short8*)&lA[ca + (wm * WM + mi * 16 + lm) * 32 + cq];
#pragma unroll
      for (int ni = 0; ni < NTT; ++ni)
        bfr[ni] =
            *(const short8*)&lB[cbb + (wn * WN + ni * 16 + lm) * 32 + cq];
#pragma unroll
      for (int mi = 0; mi < MT; ++mi)
#pragma unroll
        for (int ni = 0; ni < NTT; ++ni)
          acc[mi][ni] = __builtin_amdgcn_mfma_f32_16x16x32_bf16(
              af[mi], bfr[ni], acc[mi][ni], 0, 0, 0);
      cb = (cb == 2) ? 0 : cb + 1;
      pb = (pb == 2) ? 0 : pb + 1;
    }
  } else {
    // ---- 2-buffer dbuf, __syncthreads per step ----
    if constexpr (ADT == 1) {
      f32x4 f0[AI];
#pragma unroll
      for (int i = 0; i < AI; ++i) f0[i] = *(const f32x4*)(aF[i]);
#pragma unroll
      for (int i = 0; i < AI; ++i) {
        short4v s = {(short)f2bf(f0[i][0]), (short)f2bf(f0[i][1]),
                     (short)f2bf(f0[i][2]), (short)f2bf(f0[i][3])};
        *(short4v*)&lA[(tid + i * 256) * 4] = s;
      }
    } else {
#pragma unroll
      for (int i = 0; i < AI; ++i)
        gload_lds16(aB[i], &lA[(tid + i * 256) * 8]);
    }
    if constexpr (BDT == 1) {
      f32x4 f0[BI];
#pragma unroll
      for (int i = 0; i < BI; ++i) f0[i] = *(const f32x4*)(bF[i]);
#pragma unroll
      for (int i = 0; i < BI; ++i) {
        short4v s = {(short)f2bf(f0[i][0]), (short)f2bf(f0[i][1]),
                     (short)f2bf(f0[i][2]), (short)f2bf(f0[i][3])};
        *(short4v*)&lB[(tid + i * 256) * 4] = s;
      }
    } else {
#pragma unroll
      for (int i = 0; i < BI; ++i)
        gload_lds16(bB[i], &lB[(tid + i * 256) * 8]);
    }
    __syncthreads();  // tile 0 staged (vmcnt+lgkm drained)

    int cur = 0;
    for (int k0 = 0; k0 < K; k0 += 32) {
      const int kn = k0 + 32;
      const bool more = kn < K;
      const int nxA = (cur ^ 1) * LA, nxB = (cur ^ 1) * LB;
      f32x4 fa[AI], fb[BI];
      // issue next-tile global loads (stage-early)
      if (more) {
        if constexpr (ADT == 1) {
#pragma unroll
          for (int i = 0; i < AI; ++i) fa[i] = *(const f32x4*)(aF[i] + kn);
        } else {
#pragma unroll
          for (int i = 0; i < AI; ++i)
            gload_lds16(aB[i] + kn, &lA[nxA + (tid + i * 256) * 8]);
        }
        if constexpr (BDT == 1) {
#pragma unroll
          for (int i = 0; i < BI; ++i) fb[i] = *(const f32x4*)(bF[i] + kn);
        } else {
#pragma unroll
          for (int i = 0; i < BI; ++i)
            gload_lds16(bB[i] + kn, &lB[nxB + (tid + i * 256) * 8]);
        }
      }
      // compute current tile (hides the in-flight loads)
      short8 af[MT], bf[NTT];
#pragma unroll
      for (int mi = 0; mi < MT; ++mi)
        af[mi] =
            *(const short8*)&lA[cur * LA + (wm * WM + mi * 16 + lm) * 32 + cq];
#pragma unroll
      for (int ni = 0; ni < NTT; ++ni)
        bf[ni] =
            *(const short8*)&lB[cur * LB + (wn * WN + ni * 16 + lm) * 32 + cq];
#pragma unroll
      for (int mi = 0; mi < MT; ++mi)
#pragma unroll
        for (int ni = 0; ni < NTT; ++ni)
          acc[mi][ni] = __builtin_amdgcn_mfma_f32_16x16x32_bf16(
              af[mi], bf[ni], acc[mi][ni], 0, 0, 0);
      // late convert+ds_write for fp32 operands (vmcnt-wait lands post-MFMA)
      if (more) {
        if constexpr (ADT == 1) {
#pragma unroll
          for (int i = 0; i < AI; ++i) {
            short4v s = {(short)f2bf(fa[i][0]), (short)f2bf(fa[i][1]),
                         (short)f2bf(fa[i][2]), (short)f2bf(fa[i][3])};
            *(short4v*)&lA[nxA + (tid + i * 256) * 4] = s;
          }
        }
        if constexpr (BDT == 1) {
#pragma unroll
          for (int i = 0; i < BI; ++i) {
            short4v s = {(short)f2bf(fb[i][0]), (short)f2bf(fb[i][1]),
                         (short)f2bf(fb[i][2]), (short)f2bf(fb[i][3])};
            *(short4v*)&lB[nxB + (tid + i * 256) * 4] = s;
          }
        }
      }
      __syncthreads();  // next tile ready; current buffer free for overwrite
      cur ^= 1;
    }
  }

#pragma unroll
  for (int mi = 0; mi < MT; ++mi) {
    int rbase = m0 + wm * WM + mi * 16 + q * 4;
#pragma unroll
    for (int ni = 0; ni < NTT; ++ni) {
      int ocol = n0 + wn * WN + ni * 16 + lm;
#pragma unroll
      for (int r = 0; r < 4; ++r) {
        int orow = rbase + r;
        float v = acc[mi][ni][r];
        if (role) {
          if (orow < 1024) {
            u16 ov = f2bf(v);
            jb.c[pi][(long)orow * 1024 + ocol] = ov;
            if (jb.ct[pi]) jb.ct[pi][(long)ocol * 1024 + orow] = ov;
          }
          continue;
        }
        if (orow >= Mrows) continue;
        if constexpr (EPI == 7) {
          long urow = 8L * orow + (zpl + 1);
          float vv = v + addf[urow * 1024 + ocol];
          Yout[urow * 1024 + ocol] = vv;
          continue;
        }
        if constexpr (EPI == 5) {
          v += bias[ocol];
          bool isT0 = (orow & 2047) == 0;
          if (isT0) v = addf[(long)orow * 1024 + ocol];  // y0 = x[:,0] exact
          ((float*)Cv)[(long)orow * ldc + ocol] = v;
          if (isT0) Yout[((long)(orow >> 11) * 257) * 1024 + ocol] = v;
          if ((orow & 7) == 1)
            aux16[((long)(orow >> 3)) * 1024 + ocol] = f2bf(v);
          continue;
        }
        if constexpr (EPI == 6) {
          v += addf[(long)orow * 1024 + ocol];
          ((float*)Cv)[(long)orow * ldc + ocol] = v;
          int b = orow / 257;
          int pp_ = orow - b * 257;
          if (pp_ < 256)
            aux16[((long)(b * 256 + pp_)) * 1024 + ocol] = f2bf(v);
          if (pp_ >= 1 && pp_ < 256)
            Yout[((long)b * 2048 + 8L * pp_) * 1024 + ocol] = v;
          continue;
        }
        long urow = 0;
        bool uok = true;
        if constexpr (EPI == 2 || EPI == 3) {
          urow = 8L * orow + jp1;
          uok = ((urow & 2047) != 0);  // t==0 (mod L) slot invalid
          if (uok) v += addf[urow * 1024 + ocol];
        }
        if constexpr (EPI == 4) v += addf[(long)orow * 1024 + ocol];
        long wrow = orow;
        if constexpr (OMAP == 1)
          wrow = (long)(orow >> 8) * 257 + (orow & 255) + 1;
        if constexpr (COUT == 1)
          ((float*)Cv)[wrow * (long)ldc + ocol] = v;
        else
          ((u16*)Cv)[wrow * (long)ldc + ocol] = f2bf(v);
        if constexpr (TRW == 1) aux16[(long)ocol * ldc + orow] = f2bf(v);
        if constexpr (EPI == 3) {
          if (uok) Yout[urow * 1024 + ocol] = v;
        }
      }
    }
  }
}

// ---------------------------------------------------------------------------
// helpers
// ---------------------------------------------------------------------------
// WxT[d,k] = rc_w[k,d]; WyT[d,k] = rc_w[k,1024+d] + rc_w[k,2048+d].
// Block (0,0) also zero-fills the zrow buffers (first consumer: phase 2).
__global__ void prep_wt(const float* __restrict__ rc_w, u16* __restrict__ WxT,
                        u16* __restrict__ WyT, float* zF, u16* zB) {
  __shared__ u16 tx[64][65];
  __shared__ u16 ty[64][65];
  if (blockIdx.x == 0 && blockIdx.y == 0) {
    for (int i = threadIdx.x; i < 2048; i += 256) {
      zF[i] = 0.f;
      zB[i] = 0;
    }
  }
  int kb = blockIdx.x * 64, db = blockIdx.y * 64;
  for (int i = threadIdx.x; i < 64 * 64; i += 256) {
    int r = i >> 6, c = i & 63;
    long base = (long)(kb + r) * 3072 + db + c;
    tx[r][c] = f2bf(rc_w[base]);
    ty[r][c] = f2bf(rc_w[base + 1024] + rc_w[base + 2048]);
  }
  __syncthreads();
  for (int i = threadIdx.x; i < 64 * 64; i += 256) {
    int r = i >> 6, c = i & 63;
    WxT[(long)(db + r) * 1024 + kb + c] = tx[c][r];
    WyT[(long)(db + r) * 1024 + kb + c] = ty[c][r];
  }
}

// ---------------------------------------------------------------------------
extern "C" void kernel_launch(void* const* d_in, const int* in_sizes, int n_in,
                              void* d_out, int out_size, void* d_ws,
                              size_t ws_size, hipStream_t stream) {
  const float* x = (const float*)d_in[0];
  const float* A_w = (const float*)d_in[1];
  const float* C_w = (const float*)d_in[2];
  const float* rc_w = (const float*)d_in[3];
  const float* rc_b = (const float*)d_in[4];
  float* Y = (float*)d_out;  // fp32 U, then final y (same-element RMW)

  char* ws = (char*)d_ws;
  const long MB = 1 << 20;
  u16* Z0 = (u16*)(ws);                 // 4 MB
  u16* Z1 = (u16*)(ws + 4 * MB);        // 4 MB
  float* Bnd0 = (float*)(ws + 8 * MB);  // 2056*1024*4 (reserve 8.5 MB)
  float* Bnd1 = (float*)(ws + 8 * MB + 8912896);
  char* p = ws + 25 * MB;
  u16* Mbuf = (u16*)p;                       // 2 MB
  u16* WxT = (u16*)(p + 2 * MB);             // 2 MB
  u16* WyT = (u16*)(p + 4 * MB);             // 2 MB
  u16* Pbuf = (u16*)(p + 6 * MB);            // 2 MB
  u16* Qbuf = (u16*)(p + 8 * MB);            // 2 MB
  u16* QbufT = (u16*)(p + 10 * MB);          // 2 MB
  float* cvec = (float*)(p + 12 * MB);       // 4 KB
  float* zF = (float*)(p + 12 * MB + 4096);  // 8 KB zeros
  u16* zB = (u16*)(p + 12 * MB + 12288);     // 4 KB zeros
  u16* xbf = (u16*)(p + 12 * MB + 16384);    // 32 MB: x-bf16, then powers
  const size_t need_fast = (size_t)(25 * MB + 12 * MB + 16384) + 33554432;
  const bool fast = ws_size >= need_fast;

  SqJobs J0{};
  dim3 blk(256);
  prep_wt<<<dim3(16, 16), blk, 0, stream>>>(rc_w, WxT, WyT, zF, zB);

  // M = C_w @ A_w (A symmetric -> NT), both fp32; xconv rides (fast only).
  SqJobs sjM{};
  sjM.a[3] = (const u16*)x;
  sjM.c[3] = (u16*)xbf;
  gemm_nt<64, 64, 1, 1, 0, 0, 0, 0, 0, 0, 1>
      <<<dim3(fast ? 80 : 16, 16), blk, 0, stream>>>(
          C_w, 1024, A_w, 1024, Mbuf, 1024, 1024, 1024, zF, zB, nullptr,
          nullptr, nullptr, nullptr, 0, 0, sjM);
  // Q = M @ Wy (emits Q^T too); P = M @ Wx rides (x>=16); matvec rides
  // (x>=32): cvec = bf16(Mbuf) @ rc_b.
  SqJobs sjPQ{};
  sjPQ.a[0] = Mbuf;
  sjPQ.b[0] = WxT;
  sjPQ.c[0] = Pbuf;
  sjPQ.b[3] = (const u16*)rc_b;
  sjPQ.ct[3] = (u16*)cvec;
  gemm_nt<64, 64, 0, 0, 0, 0, 0, 0, 1, 16, 2>
      <<<dim3(48, 16), blk, 0, stream>>>(Mbuf, 1024, WyT, 1024, Qbuf, 1024,
                                         1024, 1024, zF, zB, nullptr, nullptr,
                                         nullptr, QbufT, 0, 0, sjPQ);

  // U[t,:] = x[t,:]@P^T + c -> d_out fp32 (EPI5 also: y0/Bnd0-p0 from x,
  // Z0 seed rows t%8==1)
  if (fast)
    gemm_nt<128, 128, 0, 0, 5, 0, 0, 1, 0, 0, 0>
        <<<dim3(128, 8), blk, 0, stream>>>(xbf, 1024, Pbuf, 1024, Y, 1024,
                                           16384, 1024, zF, zB, cvec, x, Bnd0,
                                           Z0, 0, 0, J0);
  else
    gemm_nt<128, 128, 1, 0, 5, 0, 0, 1, 0, 0, 0>
        <<<dim3(128, 8), blk, 0, stream>>>(x, 1024, Pbuf, 1024, Y, 1024, 16384,
                                           1024, zF, zB, cvec, x, Bnd0, Z0, 0,
                                           0, J0);

  if (fast) {
    // ---- fast pipeline: locals saved to Y in phase 1; phase 3 is ONE
    // ---- dispatch of 7 independent correction GEMMs (Y += Z0 @ Q^j^T).
    const long M1 = 1048576;  // one 1024x1024 bf16 matrix, in u16 elements
    u16* PW = xbf;            // slot j-2 = Q^j, j=2..7
    u16* Tb2 = xbf + 6 * M1;
    u16* Tt2 = xbf + 7 * M1;
    u16* Tb3 = xbf + 8 * M1;
    u16* Tt3 = xbf + 9 * M1;
    u16* Tb4 = xbf + 10 * M1;
    u16* Tt4 = xbf + 11 * M1;
    u16* Tb5 = xbf + 12 * M1;
    u16* Tt5 = xbf + 13 * M1;
    u16* Tb6 = xbf + 14 * M1;
    u16* Tt6 = xbf + 15 * M1;
    u16* Tt0 = Mbuf;
    u16* Tt1 = WxT;
    u16* Pw3T = WyT;

    // ride-along job tables per phase-1 dispatch (j=1..6, then final)
    SqJobs sj[7] = {};
    int nsq[7] = {1, 2, 4, 1, 1, 1, 1};
    sj[0].a[0] = Qbuf;        sj[0].b[0] = QbufT; sj[0].c[0] = PW;          sj[0].ct[0] = Tt0;
    sj[1].a[0] = PW;          sj[1].b[0] = Tt0;   sj[1].c[0] = PW + 2 * M1; sj[1].ct[0] = Tt1;
    sj[1].a[1] = PW;          sj[1].b[1] = QbufT; sj[1].c[1] = PW + 1 * M1; sj[1].ct[1] = Pw3T;
    sj[2].a[0] = PW + 2 * M1; sj[2].b[0] = Tt1;   sj[2].c[0] = Tb2;         sj[2].ct[0] = Tt2;
    sj[2].a[1] = PW + 2 * M1; sj[2].b[1] = QbufT; sj[2].c[1] = PW + 3 * M1;
    sj[2].a[2] = PW + 2 * M1; sj[2].b[2] = Tt0;   sj[2].c[2] = PW + 4 * M1;
    sj[2].a[3] = PW + 2 * M1; sj[2].b[3] = Pw3T;  sj[2].c[3] = PW + 5 * M1;
    sj[3].a[0] = Tb2;         sj[3].b[0] = Tt2;   sj[3].c[0] = Tb3;         sj[3].ct[0] = Tt3;
    sj[4].a[0] = Tb3;         sj[4].b[0] = Tt3;   sj[4].c[0] = Tb4;         sj[4].ct[0] = Tt4;
    sj[5].a[0] = Tb4;         sj[5].b[0] = Tt4;   sj[5].c[0] = Tb5;         sj[5].ct[0] = Tt5;
    sj[6].a[0] = Tb5;         sj[6].b[0] = Tt5;   sj[6].c[0] = Tb6;         sj[6].ct[0] = Tt6;

    // phase 1: local chunk scans; EPI=3 writes each local prefix into Y.
    for (int j = 1; j <= 6; ++j) {
      const u16* zin = (j & 1) ? Z0 : Z1;
      u16* zout = (j & 1) ? Z1 : Z0;
      gemm_nt<64, 64, 0, 0, 3, 0, 0, 0, 0, 32, 0>
          <<<dim3(32 + 16 * nsq[j - 1], 16), blk, 0, stream>>>(
              zin, 1024, Qbuf, 1024, zout, 1024, 2048, 1024, zF, zB, nullptr,
              Y, Y, nullptr, j + 1, 0, sj[j - 1]);
    }
    // local chunk-final states -> Bnd0 (Bnd layout), + Q^128 ride
    gemm_nt<64, 64, 0, 0, 2, 0, 1, 1, 0, 32, 0>
        <<<dim3(48, 16), blk, 0, stream>>>(Z0, 1024, Qbuf, 1024, Bnd0, 1024,
                                           2048, 1024, zF, zB, nullptr, Y,
                                           nullptr, nullptr, 8, 0, sj[6]);

    // phase 2: truncated Hillis-Steele over boundaries; final round emits Z0
    // inits AND the t%8==0 rows of Y.
    u16* TbP2[5] = {Tb2, Tb3, Tb4, Tb5, Tb6};
    float* bc = Bnd0;
    float* bn = Bnd1;
    for (int s = 0; s < 5; ++s) {
      if (s < 4)
        gemm_nt<64, 64, 1, 0, 4, 1, 0, 1, 0, 0, 0>
            <<<dim3(33, 16), blk, 0, stream>>>(bc, 1024, TbP2[s], 1024, bn,
                                               1024, 2056, 1024, zF, zB,
                                               nullptr, bc, nullptr, nullptr,
                                               0, 1 << s, J0);
      else
        gemm_nt<64, 64, 1, 0, 6, 1, 0, 1, 0, 0, 0>
            <<<dim3(33, 16), blk, 0, stream>>>(bc, 1024, TbP2[s], 1024, bn,
                                               1024, 2056, 1024, zF, zB,
                                               nullptr, bc, Y, Z0, 0, 1 << s,
                                               J0);
      float* t = bc;
      bc = bn;
      bn = t;
    }

    // phase 3 (collapsed): Y[8c+j] = local(already in Y) + Q^j @ y_{8c},
    // j=1..7 parallel; XCD-pinned plane remap inside the kernel (EPI7).
    SqJobs cj{};
    cj.a[0] = PW;  // Q^2.. base; plane 0 uses Bv (=Q)
    gemm_nt<64, 64, 0, 0, 7, 0, 0, 0, 0, 0, 0>
        <<<dim3(32, 16, 7), blk, 0, stream>>>(Z0, 1024, Qbuf, 1024, Z1, 1024,
                                              2048, 1024, zF, zB, nullptr, Y,
                                              Y, nullptr, 0, 0, cj);
  } else {
    // ---- slow pipeline (small workspace): original serial structure ----
    u16* Tb[7];
    u16* Tt[7];
    for (int i = 0; i < 7; ++i) {
      Tb[i] = (i & 1) ? Mbuf : WxT;
      Tt[i] = (i & 1) ? Pbuf : WyT;
    }
    for (int j = 1; j <= 6; ++j) {
      const u16* zin = (j & 1) ? Z0 : Z1;
      u16* zout = (j & 1) ? Z1 : Z0;
      gemm_nt<64, 64, 0, 0, 2, 0, 0, 0, 0, 0, 0>
          <<<dim3(32, 16), blk, 0, stream>>>(zin, 1024, Qbuf, 1024, zout, 1024,
                                             2048, 1024, zF, zB, nullptr, Y,
                                             nullptr, nullptr, j + 1, 0, J0);
    }
    gemm_nt<64, 64, 0, 0, 2, 0, 1, 1, 0, 0, 0>
        <<<dim3(32, 16), blk, 0, stream>>>(Z0, 1024, Qbuf, 1024, Bnd0, 1024,
                                           2048, 1024, zF, zB, nullptr, Y,
                                           nullptr, nullptr, 8, 0, J0);
    for (int i = 0; i < 3; ++i) {
      const u16* si = (i == 0) ? Qbuf : Tb[i - 1];
      const u16* st = (i == 0) ? QbufT : Tt[i - 1];
      gemm_nt<64, 64, 0, 0, 0, 0, 0, 0, 1, 0, 0>
          <<<dim3(16, 16), blk, 0, stream>>>(si, 1024, st, 1024, Tb[i], 1024,
                                             1024, 1024, zF, zB, nullptr,
                                             nullptr, nullptr, Tt[i], 0, 0,
                                             J0);
    }
    float* bc = Bnd0;
    float* bn = Bnd1;
    for (int s = 0; s < 5; ++s) {
      if (s < 4)
        gemm_nt<64, 64, 1, 0, 4, 1, 0, 1, 0, 0, 0>
            <<<dim3(33, 16), blk, 0, stream>>>(bc, 1024, Tb[s + 2], 1024, bn,
                                               1024, 2056, 1024, zF, zB,
                                               nullptr, bc, nullptr, nullptr,
                                               0, 1 << s, J0);
      else
        gemm_nt<64, 64, 1, 0, 6, 1, 0, 1, 0, 0, 0>
            <<<dim3(33, 16), blk, 0, stream>>>(bc, 1024, Tb[s + 2], 1024, bn,
                                               1024, 2056, 1024, zF, zB,
                                               nullptr, bc, Y, Z0, 0, 1 << s,
                                               J0);
      if (s < 4) {
        int i = s + 3;
        gemm_nt<64, 64, 0, 0, 0, 0, 0, 0, 1, 0, 0>
            <<<dim3(16, 16), blk, 0, stream>>>(Tb[i - 1], 1024, Tt[i - 1],
                                               1024, Tb[i], 1024, 1024, 1024,
                                               zF, zB, nullptr, nullptr,
                                               nullptr, Tt[i], 0, 0, J0);
      }
      float* t = bc;
      bc = bn;
      bn = t;
    }
    for (int j = 0; j <= 7; ++j) {
      const u16* zin = (j & 1) ? Z1 : Z0;
      u16* zout = (j & 1) ? Z0 : Z1;
      gemm_nt<64, 64, 0, 0, 3, 0, 0, 0, 0, 0, 0>
          <<<dim3(32, 16), blk, 0, stream>>>(zin, 1024, Qbuf, 1024, zout, 1024,
                                             2048, 1024, zF, zB, nullptr, Y, Y,
                                             nullptr, j + 1, 0, J0);
    }
  }
}